// Round 10
// baseline (497.795 us; speedup 1.0000x reference)
//
#include <hip/hip_runtime.h>

// UpBlock: deconv(8-oct GEMM) -> BN+ELU -> 27-tap gather conv -> BN+ELU
// R10: eliminate bf16 h intermediate via recompute. Pass A: GEMM -> BN1
// stats + per-channel h min/max, NO stores. Pass B: GEMM with swapped MFMA
// operands (lane holds 4 consecutive channels of one child) -> BN+ELU+quant
// -> LDS transpose -> packed y8 [N_CHILD][64B] coalesced writes.

#define N_PARENT 65536
#define C_IN     128
#define C_OUT    64
#define N_CHILD  (N_PARENT * 8)
#define TAPS     27
#define NBINS    64

typedef __bf16 bf16x8 __attribute__((ext_vector_type(8)));
typedef float  f32x4  __attribute__((ext_vector_type(4)));
typedef int    i32x4  __attribute__((ext_vector_type(4)));
typedef unsigned u32x4 __attribute__((ext_vector_type(4)));

// workspace layout (bytes)
#define Y8_OFF    0u          // i8 y8 [N_CHILD][64] = 33554432
#define WTUP_OFF  33554432u   // bf16 WtUp [8][64 n][128 k] = 131072
#define W8CV_OFF  33685504u   // i8 Wt8 [27][64 d][64 c] = 110592
#define CHMAX_OFF 33796096u   // u32 keyed per-channel max of h [64] = 256
#define CHMIN_OFF 33796352u   // u32 keyed per-channel min of h [64] = 256
#define SINV_OFF  33796608u   // f32 127/chabs [64] = 256
#define SCL_OFF   33796864u   // f32 chabs/127 [64] = 256
#define S1_OFF    33797120u   // f32 bins1 [64][128] = 32768
#define S2_OFF    33829888u   // f32 bins2 [64][128] = 32768
#define AB1_OFF   33862656u   // f32 a1[64], b1[64] = 512
#define AB2_OFF   33863168u   // f32 a2[64], b2[64] = 512
#define ZERO_LEN  (33863680u - CHMAX_OFF)

__device__ __forceinline__ float elu_f(float f) {
    return f > 0.f ? f : (__expf(f) - 1.f);
}
// order-preserving float<->uint key for atomic max/min on signed floats
__device__ __forceinline__ unsigned fkey(float f) {
    unsigned b = __float_as_uint(f);
    return (b & 0x80000000u) ? ~b : (b | 0x80000000u);
}
__device__ __forceinline__ float fdec(unsigned k) {
    unsigned b = (k & 0x80000000u) ? (k & 0x7fffffffu) : ~k;
    return __uint_as_float(b);
}

// ---- prep: WtUp transpose -> bf16 [8][64 n][128 k] ----
__global__ __launch_bounds__(256) void prep_wup(const float* __restrict__ wup,
                                                __bf16* __restrict__ wtup) {
    int i = blockIdx.x * 256 + threadIdx.x;        // 65536
    int o = i >> 13, rem = i & 8191, n = rem >> 7, k = rem & 127;
    wtup[i] = (__bf16)wup[o * 8192 + k * 64 + n];
}

// ---- pass A: h = x @ W_up (registers only) -> BN1 stats + h min/max ----
__global__ __launch_bounds__(256) void deconv_stats(
    const float* __restrict__ x, const __bf16* __restrict__ wtup,
    float* __restrict__ bins,
    unsigned* __restrict__ chmax, unsigned* __restrict__ chmin) {
    __shared__ float ssum[64], ssq[64];
    __shared__ unsigned smax[64], smin[64];
    int tid = threadIdx.x;
    int wave = tid >> 6, lane = tid & 63, lr = lane & 15, lg = lane >> 4;
    int p0 = blockIdx.x * 16;

    if (tid < 64) { ssum[tid] = 0.f; ssq[tid] = 0.f; smax[tid] = 0u; smin[tid] = 0xFFFFFFFFu; }

    const float* xrow = x + (size_t)(p0 + lr) * C_IN;
    bf16x8 afr[4];
#pragma unroll
    for (int ks = 0; ks < 4; ++ks) {
        const float* src = xrow + ks * 32 + lg * 8;
        f32x4 u0 = *(const f32x4*)(src);
        f32x4 u1 = *(const f32x4*)(src + 4);
        bf16x8 a;
#pragma unroll
        for (int i = 0; i < 4; ++i) { a[i] = (__bf16)u0[i]; a[4 + i] = (__bf16)u1[i]; }
        afr[ks] = a;
    }

    float lsum[4] = {0.f, 0.f, 0.f, 0.f}, lsq[4] = {0.f, 0.f, 0.f, 0.f};
    float hx[4] = {-3e38f, -3e38f, -3e38f, -3e38f};
    float hn[4] = {3e38f, 3e38f, 3e38f, 3e38f};
#pragma unroll
    for (int oo = 0; oo < 2; ++oo) {
        int oct = wave * 2 + oo;
#pragma unroll
        for (int nt = 0; nt < 4; ++nt) {
            f32x4 acc = {0.f, 0.f, 0.f, 0.f};
#pragma unroll
            for (int ks = 0; ks < 4; ++ks) {
                const __bf16* bp = wtup + ((size_t)(oct * 64 + nt * 16 + lr) * C_IN + ks * 32 + lg * 8);
                bf16x8 b = *(const bf16x8*)bp;
                acc = __builtin_amdgcn_mfma_f32_16x16x32_bf16(afr[ks], b, acc, 0, 0, 0);
            }
#pragma unroll
            for (int r = 0; r < 4; ++r) {
                float v = acc[r];
                lsum[nt] += v; lsq[nt] += v * v;
                hx[nt] = fmaxf(hx[nt], v); hn[nt] = fminf(hn[nt], v);
            }
        }
    }
    __syncthreads();
#pragma unroll
    for (int nt = 0; nt < 4; ++nt) {
        atomicAdd(&ssum[nt * 16 + lr], lsum[nt]);
        atomicAdd(&ssq[nt * 16 + lr], lsq[nt]);
        atomicMax(&smax[nt * 16 + lr], fkey(hx[nt]));
        atomicMin(&smin[nt * 16 + lr], fkey(hn[nt]));
    }
    __syncthreads();
    if (tid < 64) {
        float* b = bins + (size_t)(blockIdx.x & (NBINS - 1)) * 128;
        atomicAdd(&b[tid], ssum[tid]);
        atomicAdd(&b[64 + tid], ssq[tid]);
        atomicMax(&chmax[tid], smax[tid]);
        atomicMin(&chmin[tid], smin[tid]);
    }
}

// ---- finalize BN1: ab = (a,b), plus quant range from h min/max ----
__global__ void finalize_bn1(const float* __restrict__ bins,
                             const float* __restrict__ gamma,
                             const float* __restrict__ beta,
                             const unsigned* __restrict__ chmax,
                             const unsigned* __restrict__ chmin,
                             float* __restrict__ ab,
                             float* __restrict__ sinv, float* __restrict__ scl,
                             float invN) {
    int c = threadIdx.x;  // 64 threads
    float s = 0.f, q = 0.f;
    for (int b = 0; b < NBINS; ++b) { s += bins[b * 128 + c]; q += bins[b * 128 + 64 + c]; }
    float mu = s * invN;
    float var = q * invN - mu * mu;
    float rstd = rsqrtf(var + 1e-5f);
    float a = gamma[c] * rstd;
    float b = beta[c] - mu * a;
    ab[c] = a;
    ab[64 + c] = b;
    float hmx = fdec(chmax[c]), hmn = fdec(chmin[c]);
    float t0 = a * hmx + b, t1 = a * hmn + b;
    float fhi = elu_f(fmaxf(t0, t1));
    float flo = elu_f(fminf(t0, t1));
    float chabs = fmaxf(fmaxf(fhi, -flo), 1e-6f) * 1.0005f;
    sinv[c] = 127.f / chabs;
    scl[c] = chabs * (1.f / 127.f);
}

// ---- finalize BN2: per-channel a = gamma*rstd, b = beta - mu*a ----
__global__ void finalize_stats(const float* __restrict__ bins,
                               const float* __restrict__ gamma,
                               const float* __restrict__ beta,
                               float* __restrict__ ab, float invN) {
    int c = threadIdx.x;  // 64 threads
    float s = 0.f, q = 0.f;
    for (int b = 0; b < NBINS; ++b) { s += bins[b * 128 + c]; q += bins[b * 128 + 64 + c]; }
    float mu = s * invN;
    float var = q * invN - mu * mu;
    float rstd = rsqrtf(var + 1e-5f);
    float a = gamma[c] * rstd;
    ab[c] = a;
    ab[64 + c] = beta[c] - mu * a;
}

// ---- prep_w8: fold per-channel y scale into int8 W_conv ----
// w8[k][d][c] = round(wcv[k][c][d] * scl_c * T_d); T_d cancels in BN2.
__global__ __launch_bounds__(256) void prep_w8(const float* __restrict__ wcv,
                                               const float* __restrict__ scl,
                                               signed char* __restrict__ w8) {
    __shared__ float scl_s[64];
    __shared__ float red[4];
    __shared__ float tds;
    int d = blockIdx.x, t = threadIdx.x;
    if (t < 64) scl_s[t] = scl[t];
    __syncthreads();
    float m = 0.f;
    for (int i = t; i < 1728; i += 256) m = fmaxf(m, fabsf(wcv[i * 64 + d]) * scl_s[i & 63]);
#pragma unroll
    for (int dd = 1; dd < 64; dd <<= 1) m = fmaxf(m, __shfl_xor(m, dd));
    if ((t & 63) == 0) red[t >> 6] = m;
    __syncthreads();
    if (t == 0) {
        float mm = fmaxf(fmaxf(red[0], red[1]), fmaxf(red[2], red[3]));
        tds = 127.f / fmaxf(mm, 1e-20f);
    }
    __syncthreads();
    float T = tds;
    for (int i = t; i < 1728; i += 256) {
        int k = i >> 6, c = i & 63;
        float v = wcv[i * 64 + d] * scl_s[c] * T;
        w8[k * 4096 + d * 64 + c] = (signed char)(int)rintf(v);
    }
}

// ---- pass B: recompute h with SWAPPED operands, BN+ELU+quant, packed y8 ----
// D: col=lane&15 -> parent p0+lr, row=(lane>>4)*4+r -> channel nt*16+lg*4+r.
// Lane packs 4 consecutive channels into one u32 -> LDS [128][17] transpose
// -> coalesced 32B/thread stores to y8[child][64B].
__global__ __launch_bounds__(256) void quant_recompute(
    const float* __restrict__ x, const __bf16* __restrict__ wtup,
    const float* __restrict__ ab, const float* __restrict__ sinv,
    signed char* __restrict__ y8) {
    __shared__ unsigned ytile[128][17];
    int tid = threadIdx.x;
    int wave = tid >> 6, lane = tid & 63, lr = lane & 15, lg = lane >> 4;
    int p0 = blockIdx.x * 16;

    // B-operand fragments: x rows (parents)
    const float* xrow = x + (size_t)(p0 + lr) * C_IN;
    bf16x8 xf[4];
#pragma unroll
    for (int ks = 0; ks < 4; ++ks) {
        const float* src = xrow + ks * 32 + lg * 8;
        f32x4 u0 = *(const f32x4*)(src);
        f32x4 u1 = *(const f32x4*)(src + 4);
        bf16x8 a;
#pragma unroll
        for (int i = 0; i < 4; ++i) { a[i] = (__bf16)u0[i]; a[4 + i] = (__bf16)u1[i]; }
        xf[ks] = a;
    }

#pragma unroll
    for (int oo = 0; oo < 2; ++oo) {
        int oct = wave * 2 + oo;
#pragma unroll
        for (int nt = 0; nt < 4; ++nt) {
            f32x4 acc = {0.f, 0.f, 0.f, 0.f};
#pragma unroll
            for (int ks = 0; ks < 4; ++ks) {
                const __bf16* wp = wtup + ((size_t)(oct * 64 + nt * 16 + lr) * C_IN + ks * 32 + lg * 8);
                bf16x8 wf = *(const bf16x8*)wp;
                acc = __builtin_amdgcn_mfma_f32_16x16x32_bf16(wf, xf[ks], acc, 0, 0, 0);
            }
            int n0 = nt * 16 + lg * 4;
            f32x4 a4 = *(const f32x4*)(ab + n0);
            f32x4 b4 = *(const f32x4*)(ab + 64 + n0);
            f32x4 s4 = *(const f32x4*)(sinv + n0);
            unsigned pack = 0;
#pragma unroll
            for (int r = 0; r < 4; ++r) {
                float f = acc[r] * a4[r] + b4[r];
                float v = elu_f(f) * s4[r];
                v = fminf(fmaxf(v, -127.f), 127.f);
                int qv = (int)rintf(v);
                pack |= (unsigned)(qv & 255) << (8 * r);
            }
            ytile[lr * 8 + oct][nt * 4 + lg] = pack;
        }
    }
    __syncthreads();
    // phase 2: coalesced packed stores (child global row = p0*8 + cl)
    int cl = tid >> 1, half = tid & 1;
    unsigned w[8];
#pragma unroll
    for (int j = 0; j < 8; ++j) w[j] = ytile[cl][half * 8 + j];
    u32x4 v0, v1;
#pragma unroll
    for (int j = 0; j < 4; ++j) { v0[j] = w[j]; v1[j] = w[4 + j]; }
    char* dst = (char*)y8 + ((size_t)(p0 * 8 + cl) * 64 + half * 32);
    *(u32x4*)dst = v0;
    *(u32x4*)(dst + 16) = v1;
}

// ---- kernel C: 27-tap gather conv, direct-register gathers, i32 accum ----
// 256 thr = 4 waves; wave owns 32 rows (2 m-tiles) x 64 cols. No scales.
// Stage = 2 A-gathers + 4 B-loads = 6 VMEM ops; 2-deep, steady vmcnt(6).
__global__ __launch_bounds__(256, 4) void conv_bn_stats(
    const char* __restrict__ ybuf, const int* __restrict__ neigh,
    const signed char* __restrict__ w8,
    float* __restrict__ out, float* __restrict__ bins) {
    __shared__ __align__(16) int idxb_s[4][32 * TAPS];
    __shared__ float ssum[64], ssq[64];
    int tid = threadIdx.x;
    int wave = tid >> 6, lane = tid & 63, lr = lane & 15, lg = lane >> 4;
    int wr0 = blockIdx.x * 128 + wave * 32;

    if (tid < 64) { ssum[tid] = 0.f; ssq[tid] = 0.f; }

    int* idxb = idxb_s[wave];

    // ---- stage this wave's 32x27 neighbor indices into LDS (coalesced) ----
    {
        int base_w = wr0 * TAPS;
#pragma unroll
        for (int j = 0; j < 14; ++j) {
            int w = j * 64 + lane;
            if (w < 32 * TAPS) idxb[w] = neigh[base_w + w];
        }
    }
    asm volatile("s_waitcnt vmcnt(0) lgkmcnt(0)" ::: "memory");
    __builtin_amdgcn_sched_barrier(0);

    i32x4 iacc[2][4];
#pragma unroll
    for (int mt = 0; mt < 2; ++mt)
#pragma unroll
        for (int nt = 0; nt < 4; ++nt) iacc[mt][nt] = (i32x4){0, 0, 0, 0};

    const signed char* w8l = w8 + lr * 64 + lg * 16;   // B-fragment base

    i32x4 abuf[2][2];
    i32x4 bbuf[2][4];
    int icur[2];

    // ---- prologue: stage 0 then stage 1 (6 VMEM ops each) ----
    {
        int i00 = idxb[lr * TAPS + 0], i01 = idxb[(16 + lr) * TAPS + 0];
        abuf[0][0] = *(const i32x4*)(ybuf + (size_t)(unsigned)i00 * 64 + lg * 16);
        abuf[0][1] = *(const i32x4*)(ybuf + (size_t)(unsigned)i01 * 64 + lg * 16);
#pragma unroll
        for (int nt = 0; nt < 4; ++nt) bbuf[0][nt] = *(const i32x4*)(w8l + nt * 1024);
        __builtin_amdgcn_sched_barrier(0);
        int i10 = idxb[lr * TAPS + 1], i11 = idxb[(16 + lr) * TAPS + 1];
        abuf[1][0] = *(const i32x4*)(ybuf + (size_t)(unsigned)i10 * 64 + lg * 16);
        abuf[1][1] = *(const i32x4*)(ybuf + (size_t)(unsigned)i11 * 64 + lg * 16);
#pragma unroll
        for (int nt = 0; nt < 4; ++nt) bbuf[1][nt] = *(const i32x4*)(w8l + 4096 + nt * 1024);
        __builtin_amdgcn_sched_barrier(0);
        icur[0] = idxb[lr * TAPS + 2];
        icur[1] = idxb[(16 + lr) * TAPS + 2];
    }

#pragma unroll
    for (int k = 0; k < TAPS; ++k) {
        const int p = k & 1;
        // 1. wait: stage k complete; stage k+1 (6 ops) may remain in flight
        if (k < TAPS - 1) { asm volatile("s_waitcnt vmcnt(6)" ::: "memory"); }
        else              { asm volatile("s_waitcnt vmcnt(0)" ::: "memory"); }
        __builtin_amdgcn_sched_barrier(0);
        // 2. MFMAs accumulate i32 directly (no dequant)
#pragma unroll
        for (int nt = 0; nt < 4; ++nt) {
            iacc[0][nt] = __builtin_amdgcn_mfma_i32_16x16x64_i8(abuf[p][0], bbuf[p][nt], iacc[0][nt], 0, 0, 0);
            iacc[1][nt] = __builtin_amdgcn_mfma_i32_16x16x64_i8(abuf[p][1], bbuf[p][nt], iacc[1][nt], 0, 0, 0);
        }
        // 3. issue stage k+2 into buffers just consumed (WAR-safe)
        if (k + 2 < TAPS) {
            abuf[p][0] = *(const i32x4*)(ybuf + (size_t)(unsigned)icur[0] * 64 + lg * 16);
            abuf[p][1] = *(const i32x4*)(ybuf + (size_t)(unsigned)icur[1] * 64 + lg * 16);
#pragma unroll
            for (int nt = 0; nt < 4; ++nt)
                bbuf[p][nt] = *(const i32x4*)(w8l + (k + 2) * 4096 + nt * 1024);
            if (k + 3 < TAPS) {
                icur[0] = idxb[lr * TAPS + (k + 3)];
                icur[1] = idxb[(16 + lr) * TAPS + (k + 3)];
            }
        }
    }

    // epilogue: raw scaled acc (column factor T_d cancels in BN2)
    float lsum[4] = {0.f, 0.f, 0.f, 0.f}, lsq[4] = {0.f, 0.f, 0.f, 0.f};
#pragma unroll
    for (int mt = 0; mt < 2; ++mt)
#pragma unroll
        for (int nt = 0; nt < 4; ++nt)
#pragma unroll
            for (int r = 0; r < 4; ++r) {
                float v = (float)iacc[mt][nt][r];
                int row = wr0 + mt * 16 + lg * 4 + r;
                out[(size_t)row * C_OUT + nt * 16 + lr] = v;
                lsum[nt] += v; lsq[nt] += v * v;
            }
    __syncthreads();
#pragma unroll
    for (int nt = 0; nt < 4; ++nt) {
        atomicAdd(&ssum[nt * 16 + lr], lsum[nt]);
        atomicAdd(&ssq[nt * 16 + lr], lsq[nt]);
    }
    __syncthreads();
    if (tid < 64) {
        float* b = bins + (size_t)(blockIdx.x & (NBINS - 1)) * 128;
        atomicAdd(&b[tid], ssum[tid]);
        atomicAdd(&b[64 + tid], ssq[tid]);
    }
}

// ---- BN2 + ELU applied in place on f32 d_out ----
__global__ __launch_bounds__(256) void bn_elu_out(float* __restrict__ out,
                                                  const float* __restrict__ ab) {
    int tid = blockIdx.x * 256 + threadIdx.x;
    int c0 = (tid * 4) & 63;
    float av[4], bv[4];
#pragma unroll
    for (int j = 0; j < 4; ++j) { av[j] = ab[c0 + j]; bv[j] = ab[64 + c0 + j]; }
#pragma unroll
    for (int t = 0; t < 8; ++t) {
        size_t e = ((size_t)t * 1048576 + tid) * 4;
        f32x4 v = *(const f32x4*)(out + e);
        f32x4 o;
#pragma unroll
        for (int j = 0; j < 4; ++j) o[j] = elu_f(v[j] * av[j] + bv[j]);
        *(f32x4*)(out + e) = o;
    }
}

extern "C" void kernel_launch(void* const* d_in, const int* in_sizes, int n_in,
                              void* d_out, int out_size, void* d_ws, size_t ws_size,
                              hipStream_t stream) {
    const float* x     = (const float*)d_in[0];
    const int*   neigh = (const int*)d_in[1];
    const float* wup   = (const float*)d_in[2];
    const float* wcv   = (const float*)d_in[3];
    const float* g1    = (const float*)d_in[4];
    const float* b1    = (const float*)d_in[5];
    const float* g2    = (const float*)d_in[6];
    const float* b2    = (const float*)d_in[7];
    float* out = (float*)d_out;

    char* ws = (char*)d_ws;
    signed char* y8    = (signed char*)(ws + Y8_OFF);
    __bf16*      wtup  = (__bf16*)(ws + WTUP_OFF);
    signed char* w8    = (signed char*)(ws + W8CV_OFF);
    unsigned*    chmax = (unsigned*)(ws + CHMAX_OFF);
    unsigned*    chmin = (unsigned*)(ws + CHMIN_OFF);
    float*       sinv  = (float*)(ws + SINV_OFF);
    float*       scl   = (float*)(ws + SCL_OFF);
    float*       bins1 = (float*)(ws + S1_OFF);
    float*       bins2 = (float*)(ws + S2_OFF);
    float*       ab1   = (float*)(ws + AB1_OFF);
    float*       ab2   = (float*)(ws + AB2_OFF);

    hipMemsetAsync(ws + CHMAX_OFF, 0, ZERO_LEN, stream);
    hipMemsetAsync(ws + CHMIN_OFF, 0xFF, 256, stream);   // chmin init = +inf key

    prep_wup<<<256, 256, 0, stream>>>(wup, wtup);
    deconv_stats<<<N_PARENT / 16, 256, 0, stream>>>(x, wtup, bins1, chmax, chmin);
    finalize_bn1<<<1, 64, 0, stream>>>(bins1, g1, b1, chmax, chmin, ab1, sinv, scl, 1.f / (float)N_CHILD);
    prep_w8<<<64, 256, 0, stream>>>(wcv, scl, w8);
    quant_recompute<<<N_PARENT / 16, 256, 0, stream>>>(x, wtup, ab1, sinv, y8);
    conv_bn_stats<<<N_CHILD / 128, 256, 0, stream>>>((const char*)y8, neigh, w8, out, bins2);
    finalize_stats<<<1, 64, 0, stream>>>(bins2, g2, b2, ab2, 1.f / (float)N_CHILD);
    bn_elu_out<<<4096, 256, 0, stream>>>(out, ab2);
}

// Round 11
// 434.654 us; speedup vs baseline: 1.1453x; 1.1453x over previous
//
#include <hip/hip_runtime.h>

// UpBlock: deconv(8-oct GEMM) -> BN+ELU -> 27-tap gather conv -> BN+ELU
// R11: deconv stores h in fragment-native layout (512B-contiguous per wave
// store instr, 4x fewer store instrs, full sectors). quant_pack streams the
// fragment regions, quantizes, LDS-transposes, writes packed 64-B y8 rows
// IN PLACE (block-private region). Conv gathers packed rows (R10-proven).

#define N_PARENT 65536
#define C_IN     128
#define C_OUT    64
#define N_CHILD  (N_PARENT * 8)
#define TAPS     27
#define NBINS    64

typedef __bf16 bf16x8 __attribute__((ext_vector_type(8)));
typedef float  f32x4  __attribute__((ext_vector_type(4)));
typedef int    i32x4  __attribute__((ext_vector_type(4)));
typedef unsigned u32x2 __attribute__((ext_vector_type(2)));
typedef unsigned u32x4 __attribute__((ext_vector_type(4)));

// workspace layout (bytes)
#define H_OFF     0u          // hfrag [4096 blk][16384B]; later y8-in-place
#define WTUP_OFF  67108864u   // bf16 WtUp [8][64 n][128 k] = 131072
#define W8CV_OFF  67239936u   // i8 Wt8 [27][64 d][64 c] = 110592
#define CHMAX_OFF 67350528u   // u32 keyed per-channel max of h [64] = 256
#define CHMIN_OFF 67350784u   // u32 keyed per-channel min of h [64] = 256
#define SINV_OFF  67351040u   // f32 127/chabs [64] = 256
#define SCL_OFF   67351296u   // f32 chabs/127 [64] = 256
#define S1_OFF    67351552u   // f32 bins1 [64][128] = 32768
#define S2_OFF    67384320u   // f32 bins2 [64][128] = 32768
#define AB1_OFF   67417088u   // f32 a1[64], b1[64] = 512
#define AB2_OFF   67417600u   // f32 a2[64], b2[64] = 512
#define ZERO_LEN  (67418112u - CHMAX_OFF)

__device__ __forceinline__ float elu_f(float f) {
    return f > 0.f ? f : (__expf(f) - 1.f);
}
// order-preserving float<->uint key for atomic max/min on signed floats
__device__ __forceinline__ unsigned fkey(float f) {
    unsigned b = __float_as_uint(f);
    return (b & 0x80000000u) ? ~b : (b | 0x80000000u);
}
__device__ __forceinline__ float fdec(unsigned k) {
    unsigned b = (k & 0x80000000u) ? (k & 0x7fffffffu) : ~k;
    return __uint_as_float(b);
}
__device__ __forceinline__ unsigned short bfb(float v) {
    __bf16 b = (__bf16)v;
    union { __bf16 b; unsigned short u; } c;
    c.b = b;
    return c.u;
}

// ---- prep: WtUp transpose -> bf16 [8][64 n][128 k] ----
__global__ __launch_bounds__(256) void prep_wup(const float* __restrict__ wup,
                                                __bf16* __restrict__ wtup) {
    int i = blockIdx.x * 256 + threadIdx.x;        // 65536
    int o = i >> 13, rem = i & 8191, n = rem >> 7, k = rem & 127;
    wtup[i] = (__bf16)wup[o * 8192 + k * 64 + n];
}

// ---- kernel A: h = x @ W_up, fragment-native bf16 stores, BN1 stats ----
__global__ __launch_bounds__(256) void deconv_bn_stats(
    const float* __restrict__ x, const __bf16* __restrict__ wtup,
    char* __restrict__ hfrag, float* __restrict__ bins,
    unsigned* __restrict__ chmax, unsigned* __restrict__ chmin) {
    __shared__ float ssum[64], ssq[64];
    __shared__ unsigned smax[64], smin[64];
    int tid = threadIdx.x;
    int wave = tid >> 6, lane = tid & 63, lr = lane & 15, lg = lane >> 4;
    int p0 = blockIdx.x * 16;

    if (tid < 64) { ssum[tid] = 0.f; ssq[tid] = 0.f; smax[tid] = 0u; smin[tid] = 0xFFFFFFFFu; }

    const float* xrow = x + (size_t)(p0 + lr) * C_IN;
    bf16x8 afr[4];
#pragma unroll
    for (int ks = 0; ks < 4; ++ks) {
        const float* src = xrow + ks * 32 + lg * 8;
        f32x4 u0 = *(const f32x4*)(src);
        f32x4 u1 = *(const f32x4*)(src + 4);
        bf16x8 a;
#pragma unroll
        for (int i = 0; i < 4; ++i) { a[i] = (__bf16)u0[i]; a[4 + i] = (__bf16)u1[i]; }
        afr[ks] = a;
    }

    char* hblk = hfrag + (size_t)blockIdx.x * 16384;
    float lsum[4] = {0.f, 0.f, 0.f, 0.f}, lsq[4] = {0.f, 0.f, 0.f, 0.f};
    float hx[4] = {-3e38f, -3e38f, -3e38f, -3e38f};
    float hn[4] = {3e38f, 3e38f, 3e38f, 3e38f};
#pragma unroll
    for (int oo = 0; oo < 2; ++oo) {
        int oct = wave * 2 + oo;
#pragma unroll
        for (int nt = 0; nt < 4; ++nt) {
            f32x4 acc = {0.f, 0.f, 0.f, 0.f};
#pragma unroll
            for (int ks = 0; ks < 4; ++ks) {
                const __bf16* bp = wtup + ((size_t)(oct * 64 + nt * 16 + lr) * C_IN + ks * 32 + lg * 8);
                bf16x8 b = *(const bf16x8*)bp;
                acc = __builtin_amdgcn_mfma_f32_16x16x32_bf16(afr[ks], b, acc, 0, 0, 0);
            }
#pragma unroll
            for (int r = 0; r < 4; ++r) {
                float v = acc[r];
                lsum[nt] += v; lsq[nt] += v * v;
                hx[nt] = fmaxf(hx[nt], v); hn[nt] = fminf(hn[nt], v);
            }
            // fragment-native store: unit = (oct*4 + nt)*64 + lane, 8B/lane
            u32x2 pk;
            pk[0] = (unsigned)bfb(acc[0]) | ((unsigned)bfb(acc[1]) << 16);
            pk[1] = (unsigned)bfb(acc[2]) | ((unsigned)bfb(acc[3]) << 16);
            *(u32x2*)(hblk + ((oct * 4 + nt) * 64 + lane) * 8) = pk;
        }
    }
    __syncthreads();
#pragma unroll
    for (int nt = 0; nt < 4; ++nt) {
        atomicAdd(&ssum[nt * 16 + lr], lsum[nt]);
        atomicAdd(&ssq[nt * 16 + lr], lsq[nt]);
        atomicMax(&smax[nt * 16 + lr], fkey(hx[nt]));
        atomicMin(&smin[nt * 16 + lr], fkey(hn[nt]));
    }
    __syncthreads();
    if (tid < 64) {
        float* b = bins + (size_t)(blockIdx.x & (NBINS - 1)) * 128;
        atomicAdd(&b[tid], ssum[tid]);
        atomicAdd(&b[64 + tid], ssq[tid]);
        atomicMax(&chmax[tid], smax[tid]);
        atomicMin(&chmin[tid], smin[tid]);
    }
}

// ---- finalize BN1: ab = (a,b), plus quant range from h min/max ----
__global__ void finalize_bn1(const float* __restrict__ bins,
                             const float* __restrict__ gamma,
                             const float* __restrict__ beta,
                             const unsigned* __restrict__ chmax,
                             const unsigned* __restrict__ chmin,
                             float* __restrict__ ab,
                             float* __restrict__ sinv, float* __restrict__ scl,
                             float invN) {
    int c = threadIdx.x;  // 64 threads
    float s = 0.f, q = 0.f;
    for (int b = 0; b < NBINS; ++b) { s += bins[b * 128 + c]; q += bins[b * 128 + 64 + c]; }
    float mu = s * invN;
    float var = q * invN - mu * mu;
    float rstd = rsqrtf(var + 1e-5f);
    float a = gamma[c] * rstd;
    float b = beta[c] - mu * a;
    ab[c] = a;
    ab[64 + c] = b;
    float hmx = fdec(chmax[c]), hmn = fdec(chmin[c]);
    float t0 = a * hmx + b, t1 = a * hmn + b;
    float fhi = elu_f(fmaxf(t0, t1));
    float flo = elu_f(fminf(t0, t1));
    float chabs = fmaxf(fmaxf(fhi, -flo), 1e-6f) * 1.005f;  // bf16-rounding margin
    sinv[c] = 127.f / chabs;
    scl[c] = chabs * (1.f / 127.f);
}

// ---- finalize BN2 ----
__global__ void finalize_stats(const float* __restrict__ bins,
                               const float* __restrict__ gamma,
                               const float* __restrict__ beta,
                               float* __restrict__ ab, float invN) {
    int c = threadIdx.x;  // 64 threads
    float s = 0.f, q = 0.f;
    for (int b = 0; b < NBINS; ++b) { s += bins[b * 128 + c]; q += bins[b * 128 + 64 + c]; }
    float mu = s * invN;
    float var = q * invN - mu * mu;
    float rstd = rsqrtf(var + 1e-5f);
    float a = gamma[c] * rstd;
    ab[c] = a;
    ab[64 + c] = beta[c] - mu * a;
}

// ---- prep_w8: fold per-channel y scale into int8 W_conv ----
__global__ __launch_bounds__(256) void prep_w8(const float* __restrict__ wcv,
                                               const float* __restrict__ scl,
                                               signed char* __restrict__ w8) {
    __shared__ float scl_s[64];
    __shared__ float red[4];
    __shared__ float tds;
    int d = blockIdx.x, t = threadIdx.x;
    if (t < 64) scl_s[t] = scl[t];
    __syncthreads();
    float m = 0.f;
    for (int i = t; i < 1728; i += 256) m = fmaxf(m, fabsf(wcv[i * 64 + d]) * scl_s[i & 63]);
#pragma unroll
    for (int dd = 1; dd < 64; dd <<= 1) m = fmaxf(m, __shfl_xor(m, dd));
    if ((t & 63) == 0) red[t >> 6] = m;
    __syncthreads();
    if (t == 0) {
        float mm = fmaxf(fmaxf(red[0], red[1]), fmaxf(red[2], red[3]));
        tds = 127.f / fmaxf(mm, 1e-20f);
    }
    __syncthreads();
    float T = tds;
    for (int i = t; i < 1728; i += 256) {
        int k = i >> 6, c = i & 63;
        float v = wcv[i * 64 + d] * scl_s[c] * T;
        w8[k * 4096 + d * 64 + c] = (signed char)(int)rintf(v);
    }
}

// ---- quant_pack: stream fragment region, BN+ELU+quant, LDS transpose,
// packed 64-B y8 rows written IN PLACE over the block's own region ----
__global__ __launch_bounds__(256) void quant_pack(char* __restrict__ hbuf,
                                                  const float* __restrict__ ab,
                                                  const float* __restrict__ sinv) {
    __shared__ char y8t[128][68];
    __shared__ float a_s[64], b_s[64], s_s[64];
    int tid = threadIdx.x;
    if (tid < 64) { a_s[tid] = ab[tid]; b_s[tid] = ab[64 + tid]; s_s[tid] = sinv[tid]; }
    __syncthreads();

    char* reg = hbuf + (size_t)blockIdx.x * 16384;
#pragma unroll
    for (int j = 0; j < 4; ++j) {
        u32x4 v = *(const u32x4*)(reg + j * 4096 + tid * 16);
        int u0 = j * 512 + tid * 2;
#pragma unroll
        for (int half = 0; half < 2; ++half) {
            int u = u0 + half;
            unsigned w0 = v[half * 2], w1 = v[half * 2 + 1];
            int w8i = u >> 8, nt = (u >> 6) & 3, ln = u & 63;
            int lr = ln & 15, lg = ln >> 4;
            int col = nt * 16 + lr;
            float a = a_s[col], b = b_s[col], s = s_s[col];
            int cb = lg * 32 + w8i;
            float fr[4];
            fr[0] = __uint_as_float(w0 << 16);
            fr[1] = __uint_as_float(w0 & 0xFFFF0000u);
            fr[2] = __uint_as_float(w1 << 16);
            fr[3] = __uint_as_float(w1 & 0xFFFF0000u);
#pragma unroll
            for (int r = 0; r < 4; ++r) {
                float f = fr[r] * a + b;
                float vq = elu_f(f) * s;
                vq = fminf(fmaxf(vq, -127.f), 127.f);
                int q = (int)rintf(vq);
                y8t[cb + r * 8][col] = (char)q;
            }
        }
    }
    __syncthreads();
    // phase 2: coalesced packed stores into the SAME block region (reads done)
    int cl = tid >> 1, half = tid & 1;
    unsigned wv[8];
#pragma unroll
    for (int j = 0; j < 8; ++j)
        wv[j] = *(const unsigned*)(&y8t[cl][half * 32 + j * 4]);
    u32x4 v0, v1;
#pragma unroll
    for (int j = 0; j < 4; ++j) { v0[j] = wv[j]; v1[j] = wv[4 + j]; }
    char* dst = reg + cl * 64 + half * 32;
    *(u32x4*)dst = v0;
    *(u32x4*)(dst + 16) = v1;
}

// ---- kernel C: 27-tap gather conv, packed rows, i32 accum ----
// y8 row c lives at (c>>7)*16384 + (c&127)*64 (block-private in-place).
__global__ __launch_bounds__(256, 4) void conv_bn_stats(
    const char* __restrict__ ybuf, const int* __restrict__ neigh,
    const signed char* __restrict__ w8,
    float* __restrict__ out, float* __restrict__ bins) {
    __shared__ __align__(16) int idxb_s[4][32 * TAPS];
    __shared__ float ssum[64], ssq[64];
    int tid = threadIdx.x;
    int wave = tid >> 6, lane = tid & 63, lr = lane & 15, lg = lane >> 4;
    int wr0 = blockIdx.x * 128 + wave * 32;

    if (tid < 64) { ssum[tid] = 0.f; ssq[tid] = 0.f; }

    int* idxb = idxb_s[wave];

    {
        int base_w = wr0 * TAPS;
#pragma unroll
        for (int j = 0; j < 14; ++j) {
            int w = j * 64 + lane;
            if (w < 32 * TAPS) idxb[w] = neigh[base_w + w];
        }
    }
    asm volatile("s_waitcnt vmcnt(0) lgkmcnt(0)" ::: "memory");
    __builtin_amdgcn_sched_barrier(0);

#define YADDR(idx) (((size_t)((unsigned)(idx) >> 7) << 14) + (((unsigned)(idx) & 127u) << 6))

    i32x4 iacc[2][4];
#pragma unroll
    for (int mt = 0; mt < 2; ++mt)
#pragma unroll
        for (int nt = 0; nt < 4; ++nt) iacc[mt][nt] = (i32x4){0, 0, 0, 0};

    const signed char* w8l = w8 + lr * 64 + lg * 16;   // B-fragment base

    i32x4 abuf[2][2];
    i32x4 bbuf[2][4];
    int icur[2];

    {
        int i00 = idxb[lr * TAPS + 0], i01 = idxb[(16 + lr) * TAPS + 0];
        abuf[0][0] = *(const i32x4*)(ybuf + YADDR(i00) + lg * 16);
        abuf[0][1] = *(const i32x4*)(ybuf + YADDR(i01) + lg * 16);
#pragma unroll
        for (int nt = 0; nt < 4; ++nt) bbuf[0][nt] = *(const i32x4*)(w8l + nt * 1024);
        __builtin_amdgcn_sched_barrier(0);
        int i10 = idxb[lr * TAPS + 1], i11 = idxb[(16 + lr) * TAPS + 1];
        abuf[1][0] = *(const i32x4*)(ybuf + YADDR(i10) + lg * 16);
        abuf[1][1] = *(const i32x4*)(ybuf + YADDR(i11) + lg * 16);
#pragma unroll
        for (int nt = 0; nt < 4; ++nt) bbuf[1][nt] = *(const i32x4*)(w8l + 4096 + nt * 1024);
        __builtin_amdgcn_sched_barrier(0);
        icur[0] = idxb[lr * TAPS + 2];
        icur[1] = idxb[(16 + lr) * TAPS + 2];
    }

#pragma unroll
    for (int k = 0; k < TAPS; ++k) {
        const int p = k & 1;
        if (k < TAPS - 1) { asm volatile("s_waitcnt vmcnt(6)" ::: "memory"); }
        else              { asm volatile("s_waitcnt vmcnt(0)" ::: "memory"); }
        __builtin_amdgcn_sched_barrier(0);
#pragma unroll
        for (int nt = 0; nt < 4; ++nt) {
            iacc[0][nt] = __builtin_amdgcn_mfma_i32_16x16x64_i8(abuf[p][0], bbuf[p][nt], iacc[0][nt], 0, 0, 0);
            iacc[1][nt] = __builtin_amdgcn_mfma_i32_16x16x64_i8(abuf[p][1], bbuf[p][nt], iacc[1][nt], 0, 0, 0);
        }
        if (k + 2 < TAPS) {
            abuf[p][0] = *(const i32x4*)(ybuf + YADDR(icur[0]) + lg * 16);
            abuf[p][1] = *(const i32x4*)(ybuf + YADDR(icur[1]) + lg * 16);
#pragma unroll
            for (int nt = 0; nt < 4; ++nt)
                bbuf[p][nt] = *(const i32x4*)(w8l + (k + 2) * 4096 + nt * 1024);
            if (k + 3 < TAPS) {
                icur[0] = idxb[lr * TAPS + (k + 3)];
                icur[1] = idxb[(16 + lr) * TAPS + (k + 3)];
            }
        }
    }

    float lsum[4] = {0.f, 0.f, 0.f, 0.f}, lsq[4] = {0.f, 0.f, 0.f, 0.f};
#pragma unroll
    for (int mt = 0; mt < 2; ++mt)
#pragma unroll
        for (int nt = 0; nt < 4; ++nt)
#pragma unroll
            for (int r = 0; r < 4; ++r) {
                float v = (float)iacc[mt][nt][r];
                int row = wr0 + mt * 16 + lg * 4 + r;
                out[(size_t)row * C_OUT + nt * 16 + lr] = v;
                lsum[nt] += v; lsq[nt] += v * v;
            }
    __syncthreads();
#pragma unroll
    for (int nt = 0; nt < 4; ++nt) {
        atomicAdd(&ssum[nt * 16 + lr], lsum[nt]);
        atomicAdd(&ssq[nt * 16 + lr], lsq[nt]);
    }
    __syncthreads();
    if (tid < 64) {
        float* b = bins + (size_t)(blockIdx.x & (NBINS - 1)) * 128;
        atomicAdd(&b[tid], ssum[tid]);
        atomicAdd(&b[64 + tid], ssq[tid]);
    }
}

// ---- BN2 + ELU applied in place on f32 d_out ----
__global__ __launch_bounds__(256) void bn_elu_out(float* __restrict__ out,
                                                  const float* __restrict__ ab) {
    int tid = blockIdx.x * 256 + threadIdx.x;
    int c0 = (tid * 4) & 63;
    float av[4], bv[4];
#pragma unroll
    for (int j = 0; j < 4; ++j) { av[j] = ab[c0 + j]; bv[j] = ab[64 + c0 + j]; }
#pragma unroll
    for (int t = 0; t < 8; ++t) {
        size_t e = ((size_t)t * 1048576 + tid) * 4;
        f32x4 v = *(const f32x4*)(out + e);
        f32x4 o;
#pragma unroll
        for (int j = 0; j < 4; ++j) o[j] = elu_f(v[j] * av[j] + bv[j]);
        *(f32x4*)(out + e) = o;
    }
}

extern "C" void kernel_launch(void* const* d_in, const int* in_sizes, int n_in,
                              void* d_out, int out_size, void* d_ws, size_t ws_size,
                              hipStream_t stream) {
    const float* x     = (const float*)d_in[0];
    const int*   neigh = (const int*)d_in[1];
    const float* wup   = (const float*)d_in[2];
    const float* wcv   = (const float*)d_in[3];
    const float* g1    = (const float*)d_in[4];
    const float* b1    = (const float*)d_in[5];
    const float* g2    = (const float*)d_in[6];
    const float* b2    = (const float*)d_in[7];
    float* out = (float*)d_out;

    char* ws = (char*)d_ws;
    char*        hbuf  = ws + H_OFF;
    __bf16*      wtup  = (__bf16*)(ws + WTUP_OFF);
    signed char* w8    = (signed char*)(ws + W8CV_OFF);
    unsigned*    chmax = (unsigned*)(ws + CHMAX_OFF);
    unsigned*    chmin = (unsigned*)(ws + CHMIN_OFF);
    float*       sinv  = (float*)(ws + SINV_OFF);
    float*       scl   = (float*)(ws + SCL_OFF);
    float*       bins1 = (float*)(ws + S1_OFF);
    float*       bins2 = (float*)(ws + S2_OFF);
    float*       ab1   = (float*)(ws + AB1_OFF);
    float*       ab2   = (float*)(ws + AB2_OFF);

    hipMemsetAsync(ws + CHMAX_OFF, 0, ZERO_LEN, stream);
    hipMemsetAsync(ws + CHMIN_OFF, 0xFF, 256, stream);   // chmin init = +inf key

    prep_wup<<<256, 256, 0, stream>>>(wup, wtup);
    deconv_bn_stats<<<N_PARENT / 16, 256, 0, stream>>>(x, wtup, hbuf, bins1, chmax, chmin);
    finalize_bn1<<<1, 64, 0, stream>>>(bins1, g1, b1, chmax, chmin, ab1, sinv, scl, 1.f / (float)N_CHILD);
    prep_w8<<<64, 256, 0, stream>>>(wcv, scl, w8);
    quant_pack<<<N_PARENT / 16, 256, 0, stream>>>(hbuf, ab1, sinv);
    conv_bn_stats<<<N_CHILD / 128, 256, 0, stream>>>((const char*)hbuf, neigh, w8, out, bins2);
    finalize_stats<<<1, 64, 0, stream>>>(bins2, g2, b2, ab2, 1.f / (float)N_CHILD);
    bn_elu_out<<<4096, 256, 0, stream>>>(out, ab2);
}

// Round 12
// 416.848 us; speedup vs baseline: 1.1942x; 1.0427x over previous
//
#include <hip/hip_runtime.h>

// UpBlock: deconv(8-oct GEMM) -> BN+ELU -> 27-tap gather conv -> BN+ELU
// R12: conv raw accumulator stored as bf16 (halves conv write + final-pass
// read traffic) when ws_size permits (>=135 MB); deterministic fallback to
// the R11 f32-in-d_out path otherwise. Rest identical to R11.

#define N_PARENT 65536
#define C_IN     128
#define C_OUT    64
#define N_CHILD  (N_PARENT * 8)
#define TAPS     27
#define NBINS    64

typedef __bf16 bf16x8 __attribute__((ext_vector_type(8)));
typedef float  f32x4  __attribute__((ext_vector_type(4)));
typedef int    i32x4  __attribute__((ext_vector_type(4)));
typedef unsigned u32x2 __attribute__((ext_vector_type(2)));
typedef unsigned u32x4 __attribute__((ext_vector_type(4)));

// workspace layout (bytes)
#define H_OFF     0u          // hfrag [4096 blk][16384B]; later y8-in-place
#define WTUP_OFF  67108864u   // bf16 WtUp [8][64 n][128 k] = 131072
#define W8CV_OFF  67239936u   // i8 Wt8 [27][64 d][64 c] = 110592
#define CHMAX_OFF 67350528u   // u32 keyed per-channel max of h [64] = 256
#define CHMIN_OFF 67350784u   // u32 keyed per-channel min of h [64] = 256
#define SINV_OFF  67351040u   // f32 127/chabs [64] = 256
#define SCL_OFF   67351296u   // f32 chabs/127 [64] = 256
#define S1_OFF    67351552u   // f32 bins1 [64][128] = 32768
#define S2_OFF    67384320u   // f32 bins2 [64][128] = 32768
#define AB1_OFF   67417088u   // f32 a1[64], b1[64] = 512
#define AB2_OFF   67417600u   // f32 a2[64], b2[64] = 512
#define ZERO_LEN  (67418112u - CHMAX_OFF)
#define ACC16_OFF 67418112u   // bf16 acc [N_CHILD][64] = 67108864 (optional)
#define WS_NEED_BIG (ACC16_OFF + 67108864u)

__device__ __forceinline__ float elu_f(float f) {
    return f > 0.f ? f : (__expf(f) - 1.f);
}
// order-preserving float<->uint key for atomic max/min on signed floats
__device__ __forceinline__ unsigned fkey(float f) {
    unsigned b = __float_as_uint(f);
    return (b & 0x80000000u) ? ~b : (b | 0x80000000u);
}
__device__ __forceinline__ float fdec(unsigned k) {
    unsigned b = (k & 0x80000000u) ? (k & 0x7fffffffu) : ~k;
    return __uint_as_float(b);
}
__device__ __forceinline__ unsigned short bfb(float v) {
    __bf16 b = (__bf16)v;
    union { __bf16 b; unsigned short u; } c;
    c.b = b;
    return c.u;
}

// ---- prep: WtUp transpose -> bf16 [8][64 n][128 k] ----
__global__ __launch_bounds__(256) void prep_wup(const float* __restrict__ wup,
                                                __bf16* __restrict__ wtup) {
    int i = blockIdx.x * 256 + threadIdx.x;        // 65536
    int o = i >> 13, rem = i & 8191, n = rem >> 7, k = rem & 127;
    wtup[i] = (__bf16)wup[o * 8192 + k * 64 + n];
}

// ---- kernel A: h = x @ W_up, fragment-native bf16 stores, BN1 stats ----
__global__ __launch_bounds__(256) void deconv_bn_stats(
    const float* __restrict__ x, const __bf16* __restrict__ wtup,
    char* __restrict__ hfrag, float* __restrict__ bins,
    unsigned* __restrict__ chmax, unsigned* __restrict__ chmin) {
    __shared__ float ssum[64], ssq[64];
    __shared__ unsigned smax[64], smin[64];
    int tid = threadIdx.x;
    int wave = tid >> 6, lane = tid & 63, lr = lane & 15, lg = lane >> 4;
    int p0 = blockIdx.x * 16;

    if (tid < 64) { ssum[tid] = 0.f; ssq[tid] = 0.f; smax[tid] = 0u; smin[tid] = 0xFFFFFFFFu; }

    const float* xrow = x + (size_t)(p0 + lr) * C_IN;
    bf16x8 afr[4];
#pragma unroll
    for (int ks = 0; ks < 4; ++ks) {
        const float* src = xrow + ks * 32 + lg * 8;
        f32x4 u0 = *(const f32x4*)(src);
        f32x4 u1 = *(const f32x4*)(src + 4);
        bf16x8 a;
#pragma unroll
        for (int i = 0; i < 4; ++i) { a[i] = (__bf16)u0[i]; a[4 + i] = (__bf16)u1[i]; }
        afr[ks] = a;
    }

    char* hblk = hfrag + (size_t)blockIdx.x * 16384;
    float lsum[4] = {0.f, 0.f, 0.f, 0.f}, lsq[4] = {0.f, 0.f, 0.f, 0.f};
    float hx[4] = {-3e38f, -3e38f, -3e38f, -3e38f};
    float hn[4] = {3e38f, 3e38f, 3e38f, 3e38f};
#pragma unroll
    for (int oo = 0; oo < 2; ++oo) {
        int oct = wave * 2 + oo;
#pragma unroll
        for (int nt = 0; nt < 4; ++nt) {
            f32x4 acc = {0.f, 0.f, 0.f, 0.f};
#pragma unroll
            for (int ks = 0; ks < 4; ++ks) {
                const __bf16* bp = wtup + ((size_t)(oct * 64 + nt * 16 + lr) * C_IN + ks * 32 + lg * 8);
                bf16x8 b = *(const bf16x8*)bp;
                acc = __builtin_amdgcn_mfma_f32_16x16x32_bf16(afr[ks], b, acc, 0, 0, 0);
            }
#pragma unroll
            for (int r = 0; r < 4; ++r) {
                float v = acc[r];
                lsum[nt] += v; lsq[nt] += v * v;
                hx[nt] = fmaxf(hx[nt], v); hn[nt] = fminf(hn[nt], v);
            }
            u32x2 pk;
            pk[0] = (unsigned)bfb(acc[0]) | ((unsigned)bfb(acc[1]) << 16);
            pk[1] = (unsigned)bfb(acc[2]) | ((unsigned)bfb(acc[3]) << 16);
            *(u32x2*)(hblk + ((oct * 4 + nt) * 64 + lane) * 8) = pk;
        }
    }
    __syncthreads();
#pragma unroll
    for (int nt = 0; nt < 4; ++nt) {
        atomicAdd(&ssum[nt * 16 + lr], lsum[nt]);
        atomicAdd(&ssq[nt * 16 + lr], lsq[nt]);
        atomicMax(&smax[nt * 16 + lr], fkey(hx[nt]));
        atomicMin(&smin[nt * 16 + lr], fkey(hn[nt]));
    }
    __syncthreads();
    if (tid < 64) {
        float* b = bins + (size_t)(blockIdx.x & (NBINS - 1)) * 128;
        atomicAdd(&b[tid], ssum[tid]);
        atomicAdd(&b[64 + tid], ssq[tid]);
        atomicMax(&chmax[tid], smax[tid]);
        atomicMin(&chmin[tid], smin[tid]);
    }
}

// ---- finalize BN1: ab = (a,b), plus quant range from h min/max ----
__global__ void finalize_bn1(const float* __restrict__ bins,
                             const float* __restrict__ gamma,
                             const float* __restrict__ beta,
                             const unsigned* __restrict__ chmax,
                             const unsigned* __restrict__ chmin,
                             float* __restrict__ ab,
                             float* __restrict__ sinv, float* __restrict__ scl,
                             float invN) {
    int c = threadIdx.x;  // 64 threads
    float s = 0.f, q = 0.f;
    for (int b = 0; b < NBINS; ++b) { s += bins[b * 128 + c]; q += bins[b * 128 + 64 + c]; }
    float mu = s * invN;
    float var = q * invN - mu * mu;
    float rstd = rsqrtf(var + 1e-5f);
    float a = gamma[c] * rstd;
    float b = beta[c] - mu * a;
    ab[c] = a;
    ab[64 + c] = b;
    float hmx = fdec(chmax[c]), hmn = fdec(chmin[c]);
    float t0 = a * hmx + b, t1 = a * hmn + b;
    float fhi = elu_f(fmaxf(t0, t1));
    float flo = elu_f(fminf(t0, t1));
    float chabs = fmaxf(fmaxf(fhi, -flo), 1e-6f) * 1.005f;  // bf16-rounding margin
    sinv[c] = 127.f / chabs;
    scl[c] = chabs * (1.f / 127.f);
}

// ---- finalize BN2 ----
__global__ void finalize_stats(const float* __restrict__ bins,
                               const float* __restrict__ gamma,
                               const float* __restrict__ beta,
                               float* __restrict__ ab, float invN) {
    int c = threadIdx.x;  // 64 threads
    float s = 0.f, q = 0.f;
    for (int b = 0; b < NBINS; ++b) { s += bins[b * 128 + c]; q += bins[b * 128 + 64 + c]; }
    float mu = s * invN;
    float var = q * invN - mu * mu;
    float rstd = rsqrtf(var + 1e-5f);
    float a = gamma[c] * rstd;
    ab[c] = a;
    ab[64 + c] = beta[c] - mu * a;
}

// ---- prep_w8: fold per-channel y scale into int8 W_conv ----
__global__ __launch_bounds__(256) void prep_w8(const float* __restrict__ wcv,
                                               const float* __restrict__ scl,
                                               signed char* __restrict__ w8) {
    __shared__ float scl_s[64];
    __shared__ float red[4];
    __shared__ float tds;
    int d = blockIdx.x, t = threadIdx.x;
    if (t < 64) scl_s[t] = scl[t];
    __syncthreads();
    float m = 0.f;
    for (int i = t; i < 1728; i += 256) m = fmaxf(m, fabsf(wcv[i * 64 + d]) * scl_s[i & 63]);
#pragma unroll
    for (int dd = 1; dd < 64; dd <<= 1) m = fmaxf(m, __shfl_xor(m, dd));
    if ((t & 63) == 0) red[t >> 6] = m;
    __syncthreads();
    if (t == 0) {
        float mm = fmaxf(fmaxf(red[0], red[1]), fmaxf(red[2], red[3]));
        tds = 127.f / fmaxf(mm, 1e-20f);
    }
    __syncthreads();
    float T = tds;
    for (int i = t; i < 1728; i += 256) {
        int k = i >> 6, c = i & 63;
        float v = wcv[i * 64 + d] * scl_s[c] * T;
        w8[k * 4096 + d * 64 + c] = (signed char)(int)rintf(v);
    }
}

// ---- quant_pack: stream fragment region, BN+ELU+quant, LDS transpose,
// packed 64-B y8 rows written IN PLACE over the block's own region ----
__global__ __launch_bounds__(256) void quant_pack(char* __restrict__ hbuf,
                                                  const float* __restrict__ ab,
                                                  const float* __restrict__ sinv) {
    __shared__ char y8t[128][68];
    __shared__ float a_s[64], b_s[64], s_s[64];
    int tid = threadIdx.x;
    if (tid < 64) { a_s[tid] = ab[tid]; b_s[tid] = ab[64 + tid]; s_s[tid] = sinv[tid]; }
    __syncthreads();

    char* reg = hbuf + (size_t)blockIdx.x * 16384;
#pragma unroll
    for (int j = 0; j < 4; ++j) {
        u32x4 v = *(const u32x4*)(reg + j * 4096 + tid * 16);
        int u0 = j * 512 + tid * 2;
#pragma unroll
        for (int half = 0; half < 2; ++half) {
            int u = u0 + half;
            unsigned w0 = v[half * 2], w1 = v[half * 2 + 1];
            int w8i = u >> 8, nt = (u >> 6) & 3, ln = u & 63;
            int lr = ln & 15, lg = ln >> 4;
            int col = nt * 16 + lr;
            float a = a_s[col], b = b_s[col], s = s_s[col];
            int cb = lg * 32 + w8i;
            float fr[4];
            fr[0] = __uint_as_float(w0 << 16);
            fr[1] = __uint_as_float(w0 & 0xFFFF0000u);
            fr[2] = __uint_as_float(w1 << 16);
            fr[3] = __uint_as_float(w1 & 0xFFFF0000u);
#pragma unroll
            for (int r = 0; r < 4; ++r) {
                float f = fr[r] * a + b;
                float vq = elu_f(f) * s;
                vq = fminf(fmaxf(vq, -127.f), 127.f);
                int q = (int)rintf(vq);
                y8t[cb + r * 8][col] = (char)q;
            }
        }
    }
    __syncthreads();
    int cl = tid >> 1, half = tid & 1;
    unsigned wv[8];
#pragma unroll
    for (int j = 0; j < 8; ++j)
        wv[j] = *(const unsigned*)(&y8t[cl][half * 32 + j * 4]);
    u32x4 v0, v1;
#pragma unroll
    for (int j = 0; j < 4; ++j) { v0[j] = wv[j]; v1[j] = wv[4 + j]; }
    char* dst = reg + cl * 64 + half * 32;
    *(u32x4*)dst = v0;
    *(u32x4*)(dst + 16) = v1;
}

// ---- kernel C: 27-tap gather conv, packed rows, i32 accum ----
// ACC16: raw acc stored bf16 to accb; else f32 to outf.
template <bool ACC16>
__global__ __launch_bounds__(256, 4) void conv_bn_stats(
    const char* __restrict__ ybuf, const int* __restrict__ neigh,
    const signed char* __restrict__ w8,
    float* __restrict__ outf, unsigned short* __restrict__ accb,
    float* __restrict__ bins) {
    __shared__ __align__(16) int idxb_s[4][32 * TAPS];
    __shared__ float ssum[64], ssq[64];
    int tid = threadIdx.x;
    int wave = tid >> 6, lane = tid & 63, lr = lane & 15, lg = lane >> 4;
    int wr0 = blockIdx.x * 128 + wave * 32;

    if (tid < 64) { ssum[tid] = 0.f; ssq[tid] = 0.f; }

    int* idxb = idxb_s[wave];

    {
        int base_w = wr0 * TAPS;
#pragma unroll
        for (int j = 0; j < 14; ++j) {
            int w = j * 64 + lane;
            if (w < 32 * TAPS) idxb[w] = neigh[base_w + w];
        }
    }
    asm volatile("s_waitcnt vmcnt(0) lgkmcnt(0)" ::: "memory");
    __builtin_amdgcn_sched_barrier(0);

#define YADDR(idx) (((size_t)((unsigned)(idx) >> 7) << 14) + (((unsigned)(idx) & 127u) << 6))

    i32x4 iacc[2][4];
#pragma unroll
    for (int mt = 0; mt < 2; ++mt)
#pragma unroll
        for (int nt = 0; nt < 4; ++nt) iacc[mt][nt] = (i32x4){0, 0, 0, 0};

    const signed char* w8l = w8 + lr * 64 + lg * 16;   // B-fragment base

    i32x4 abuf[2][2];
    i32x4 bbuf[2][4];
    int icur[2];

    {
        int i00 = idxb[lr * TAPS + 0], i01 = idxb[(16 + lr) * TAPS + 0];
        abuf[0][0] = *(const i32x4*)(ybuf + YADDR(i00) + lg * 16);
        abuf[0][1] = *(const i32x4*)(ybuf + YADDR(i01) + lg * 16);
#pragma unroll
        for (int nt = 0; nt < 4; ++nt) bbuf[0][nt] = *(const i32x4*)(w8l + nt * 1024);
        __builtin_amdgcn_sched_barrier(0);
        int i10 = idxb[lr * TAPS + 1], i11 = idxb[(16 + lr) * TAPS + 1];
        abuf[1][0] = *(const i32x4*)(ybuf + YADDR(i10) + lg * 16);
        abuf[1][1] = *(const i32x4*)(ybuf + YADDR(i11) + lg * 16);
#pragma unroll
        for (int nt = 0; nt < 4; ++nt) bbuf[1][nt] = *(const i32x4*)(w8l + 4096 + nt * 1024);
        __builtin_amdgcn_sched_barrier(0);
        icur[0] = idxb[lr * TAPS + 2];
        icur[1] = idxb[(16 + lr) * TAPS + 2];
    }

#pragma unroll
    for (int k = 0; k < TAPS; ++k) {
        const int p = k & 1;
        if (k < TAPS - 1) { asm volatile("s_waitcnt vmcnt(6)" ::: "memory"); }
        else              { asm volatile("s_waitcnt vmcnt(0)" ::: "memory"); }
        __builtin_amdgcn_sched_barrier(0);
#pragma unroll
        for (int nt = 0; nt < 4; ++nt) {
            iacc[0][nt] = __builtin_amdgcn_mfma_i32_16x16x64_i8(abuf[p][0], bbuf[p][nt], iacc[0][nt], 0, 0, 0);
            iacc[1][nt] = __builtin_amdgcn_mfma_i32_16x16x64_i8(abuf[p][1], bbuf[p][nt], iacc[1][nt], 0, 0, 0);
        }
        if (k + 2 < TAPS) {
            abuf[p][0] = *(const i32x4*)(ybuf + YADDR(icur[0]) + lg * 16);
            abuf[p][1] = *(const i32x4*)(ybuf + YADDR(icur[1]) + lg * 16);
#pragma unroll
            for (int nt = 0; nt < 4; ++nt)
                bbuf[p][nt] = *(const i32x4*)(w8l + (k + 2) * 4096 + nt * 1024);
            if (k + 3 < TAPS) {
                icur[0] = idxb[lr * TAPS + (k + 3)];
                icur[1] = idxb[(16 + lr) * TAPS + (k + 3)];
            }
        }
    }

    float lsum[4] = {0.f, 0.f, 0.f, 0.f}, lsq[4] = {0.f, 0.f, 0.f, 0.f};
#pragma unroll
    for (int mt = 0; mt < 2; ++mt)
#pragma unroll
        for (int nt = 0; nt < 4; ++nt)
#pragma unroll
            for (int r = 0; r < 4; ++r) {
                float v = (float)iacc[mt][nt][r];
                int row = wr0 + mt * 16 + lg * 4 + r;
                if (ACC16) accb[(size_t)row * C_OUT + nt * 16 + lr] = bfb(v);
                else       outf[(size_t)row * C_OUT + nt * 16 + lr] = v;
                lsum[nt] += v; lsq[nt] += v * v;
            }
    __syncthreads();
#pragma unroll
    for (int nt = 0; nt < 4; ++nt) {
        atomicAdd(&ssum[nt * 16 + lr], lsum[nt]);
        atomicAdd(&ssq[nt * 16 + lr], lsq[nt]);
    }
    __syncthreads();
    if (tid < 64) {
        float* b = bins + (size_t)(blockIdx.x & (NBINS - 1)) * 128;
        atomicAdd(&b[tid], ssum[tid]);
        atomicAdd(&b[64 + tid], ssq[tid]);
    }
}

// ---- BN2 + ELU, f32 acc in place ----
__global__ __launch_bounds__(256) void bn_elu_out_f32(float* __restrict__ out,
                                                      const float* __restrict__ ab) {
    int tid = blockIdx.x * 256 + threadIdx.x;
    int c0 = (tid * 4) & 63;
    float av[4], bv[4];
#pragma unroll
    for (int j = 0; j < 4; ++j) { av[j] = ab[c0 + j]; bv[j] = ab[64 + c0 + j]; }
#pragma unroll
    for (int t = 0; t < 8; ++t) {
        size_t e = ((size_t)t * 1048576 + tid) * 4;
        f32x4 v = *(const f32x4*)(out + e);
        f32x4 o;
#pragma unroll
        for (int j = 0; j < 4; ++j) o[j] = elu_f(v[j] * av[j] + bv[j]);
        *(f32x4*)(out + e) = o;
    }
}

// ---- BN2 + ELU, bf16 acc -> f32 out ----
__global__ __launch_bounds__(256) void bn_elu_out_bf16(
    const unsigned short* __restrict__ accb, float* __restrict__ out,
    const float* __restrict__ ab) {
    int tid = blockIdx.x * 256 + threadIdx.x;
    int c0 = (tid * 8) & 63;
    float av[8], bv[8];
#pragma unroll
    for (int j = 0; j < 8; ++j) { av[j] = ab[c0 + j]; bv[j] = ab[64 + c0 + j]; }
#pragma unroll
    for (int t = 0; t < 4; ++t) {
        size_t e = ((size_t)t * 1048576 + tid) * 8;
        u32x4 v = *(const u32x4*)(accb + e);
        f32x4 o0, o1;
#pragma unroll
        for (int j = 0; j < 4; ++j) {
            unsigned w = v[j];
            float f0 = __uint_as_float(w << 16);
            float f1 = __uint_as_float(w & 0xFFFF0000u);
            float r0 = elu_f(f0 * av[j * 2] + bv[j * 2]);
            float r1 = elu_f(f1 * av[j * 2 + 1] + bv[j * 2 + 1]);
            if (j < 2) { o0[j * 2] = r0; o0[j * 2 + 1] = r1; }
            else       { o1[(j - 2) * 2] = r0; o1[(j - 2) * 2 + 1] = r1; }
        }
        *(f32x4*)(out + e) = o0;
        *(f32x4*)(out + e + 4) = o1;
    }
}

extern "C" void kernel_launch(void* const* d_in, const int* in_sizes, int n_in,
                              void* d_out, int out_size, void* d_ws, size_t ws_size,
                              hipStream_t stream) {
    const float* x     = (const float*)d_in[0];
    const int*   neigh = (const int*)d_in[1];
    const float* wup   = (const float*)d_in[2];
    const float* wcv   = (const float*)d_in[3];
    const float* g1    = (const float*)d_in[4];
    const float* b1    = (const float*)d_in[5];
    const float* g2    = (const float*)d_in[6];
    const float* b2    = (const float*)d_in[7];
    float* out = (float*)d_out;

    char* ws = (char*)d_ws;
    char*        hbuf  = ws + H_OFF;
    __bf16*      wtup  = (__bf16*)(ws + WTUP_OFF);
    signed char* w8    = (signed char*)(ws + W8CV_OFF);
    unsigned*    chmax = (unsigned*)(ws + CHMAX_OFF);
    unsigned*    chmin = (unsigned*)(ws + CHMIN_OFF);
    float*       sinv  = (float*)(ws + SINV_OFF);
    float*       scl   = (float*)(ws + SCL_OFF);
    float*       bins1 = (float*)(ws + S1_OFF);
    float*       bins2 = (float*)(ws + S2_OFF);
    float*       ab1   = (float*)(ws + AB1_OFF);
    float*       ab2   = (float*)(ws + AB2_OFF);
    unsigned short* accb = (unsigned short*)(ws + ACC16_OFF);

    const bool big = (ws_size >= (size_t)WS_NEED_BIG);

    hipMemsetAsync(ws + CHMAX_OFF, 0, ZERO_LEN, stream);
    hipMemsetAsync(ws + CHMIN_OFF, 0xFF, 256, stream);   // chmin init = +inf key

    prep_wup<<<256, 256, 0, stream>>>(wup, wtup);
    deconv_bn_stats<<<N_PARENT / 16, 256, 0, stream>>>(x, wtup, hbuf, bins1, chmax, chmin);
    finalize_bn1<<<1, 64, 0, stream>>>(bins1, g1, b1, chmax, chmin, ab1, sinv, scl, 1.f / (float)N_CHILD);
    prep_w8<<<64, 256, 0, stream>>>(wcv, scl, w8);
    quant_pack<<<N_PARENT / 16, 256, 0, stream>>>(hbuf, ab1, sinv);
    if (big) {
        conv_bn_stats<true><<<N_CHILD / 128, 256, 0, stream>>>((const char*)hbuf, neigh, w8, out, accb, bins2);
        finalize_stats<<<1, 64, 0, stream>>>(bins2, g2, b2, ab2, 1.f / (float)N_CHILD);
        bn_elu_out_bf16<<<4096, 256, 0, stream>>>(accb, out, ab2);
    } else {
        conv_bn_stats<false><<<N_CHILD / 128, 256, 0, stream>>>((const char*)hbuf, neigh, w8, out, accb, bins2);
        finalize_stats<<<1, 64, 0, stream>>>(bins2, g2, b2, ab2, 1.f / (float)N_CHILD);
        bn_elu_out_f32<<<4096, 256, 0, stream>>>(out, ab2);
    }
}

// Round 13
// 407.546 us; speedup vs baseline: 1.2214x; 1.0228x over previous
//
#include <hip/hip_runtime.h>

// UpBlock: deconv(8-oct GEMM) -> BN+ELU -> 27-tap gather conv -> BN+ELU
// R13: deconv 32 parents/block (grid 2048), B-fragments reused across two
// 16-parent groups in registers -> halves the 536 MB wtup L2 re-read.
// hfrag layout preserved; quant_pack/conv identical to R12.

#define N_PARENT 65536
#define C_IN     128
#define C_OUT    64
#define N_CHILD  (N_PARENT * 8)
#define TAPS     27
#define NBINS    64

typedef __bf16 bf16x8 __attribute__((ext_vector_type(8)));
typedef float  f32x4  __attribute__((ext_vector_type(4)));
typedef int    i32x4  __attribute__((ext_vector_type(4)));
typedef unsigned u32x2 __attribute__((ext_vector_type(2)));
typedef unsigned u32x4 __attribute__((ext_vector_type(4)));

// workspace layout (bytes)
#define H_OFF     0u          // hfrag [4096 reg][16384B]; later y8-in-place
#define WTUP_OFF  67108864u   // bf16 WtUp [8][64 n][128 k] = 131072
#define W8CV_OFF  67239936u   // i8 Wt8 [27][64 d][64 c] = 110592
#define CHMAX_OFF 67350528u   // u32 keyed per-channel max of h [64] = 256
#define CHMIN_OFF 67350784u   // u32 keyed per-channel min of h [64] = 256
#define SINV_OFF  67351040u   // f32 127/chabs [64] = 256
#define SCL_OFF   67351296u   // f32 chabs/127 [64] = 256
#define S1_OFF    67351552u   // f32 bins1 [64][128] = 32768
#define S2_OFF    67384320u   // f32 bins2 [64][128] = 32768
#define AB1_OFF   67417088u   // f32 a1[64], b1[64] = 512
#define AB2_OFF   67417600u   // f32 a2[64], b2[64] = 512
#define ZERO_LEN  (67418112u - CHMAX_OFF)
#define ACC16_OFF 67418112u   // bf16 acc [N_CHILD][64] = 67108864 (optional)
#define WS_NEED_BIG (ACC16_OFF + 67108864u)

__device__ __forceinline__ float elu_f(float f) {
    return f > 0.f ? f : (__expf(f) - 1.f);
}
// order-preserving float<->uint key for atomic max/min on signed floats
__device__ __forceinline__ unsigned fkey(float f) {
    unsigned b = __float_as_uint(f);
    return (b & 0x80000000u) ? ~b : (b | 0x80000000u);
}
__device__ __forceinline__ float fdec(unsigned k) {
    unsigned b = (k & 0x80000000u) ? (k & 0x7fffffffu) : ~k;
    return __uint_as_float(b);
}
__device__ __forceinline__ unsigned short bfb(float v) {
    __bf16 b = (__bf16)v;
    union { __bf16 b; unsigned short u; } c;
    c.b = b;
    return c.u;
}

// ---- prep: WtUp transpose -> bf16 [8][64 n][128 k] ----
__global__ __launch_bounds__(256) void prep_wup(const float* __restrict__ wup,
                                                __bf16* __restrict__ wtup) {
    int i = blockIdx.x * 256 + threadIdx.x;        // 65536
    int o = i >> 13, rem = i & 8191, n = rem >> 7, k = rem & 127;
    wtup[i] = (__bf16)wup[o * 8192 + k * 64 + n];
}

// ---- kernel A: h = x @ W_up, 32 parents/block, B-frag reuse x2 ----
__global__ __launch_bounds__(256, 4) void deconv_bn_stats(
    const float* __restrict__ x, const __bf16* __restrict__ wtup,
    char* __restrict__ hfrag, float* __restrict__ bins,
    unsigned* __restrict__ chmax, unsigned* __restrict__ chmin) {
    __shared__ float ssum[64], ssq[64];
    __shared__ unsigned smax[64], smin[64];
    int tid = threadIdx.x;
    int wave = tid >> 6, lane = tid & 63, lr = lane & 15, lg = lane >> 4;
    int p0 = blockIdx.x * 32;

    if (tid < 64) { ssum[tid] = 0.f; ssq[tid] = 0.f; smax[tid] = 0u; smin[tid] = 0xFFFFFFFFu; }

    // A-fragments for both 16-parent groups
    bf16x8 afr[2][4];
#pragma unroll
    for (int g = 0; g < 2; ++g) {
        const float* xrow = x + (size_t)(p0 + g * 16 + lr) * C_IN;
#pragma unroll
        for (int ks = 0; ks < 4; ++ks) {
            const float* src = xrow + ks * 32 + lg * 8;
            f32x4 u0 = *(const f32x4*)(src);
            f32x4 u1 = *(const f32x4*)(src + 4);
            bf16x8 a;
#pragma unroll
            for (int i = 0; i < 4; ++i) { a[i] = (__bf16)u0[i]; a[4 + i] = (__bf16)u1[i]; }
            afr[g][ks] = a;
        }
    }

    char* hblk0 = hfrag + (size_t)(blockIdx.x * 2) * 16384;
    char* hblk1 = hblk0 + 16384;

    float lsum[4] = {0.f, 0.f, 0.f, 0.f}, lsq[4] = {0.f, 0.f, 0.f, 0.f};
    float hx[4] = {-3e38f, -3e38f, -3e38f, -3e38f};
    float hn[4] = {3e38f, 3e38f, 3e38f, 3e38f};
#pragma unroll
    for (int oo = 0; oo < 2; ++oo) {
        int oct = wave * 2 + oo;
#pragma unroll
        for (int nt = 0; nt < 4; ++nt) {
            bf16x8 b[4];
#pragma unroll
            for (int ks = 0; ks < 4; ++ks)
                b[ks] = *(const bf16x8*)(wtup + ((size_t)(oct * 64 + nt * 16 + lr) * C_IN + ks * 32 + lg * 8));
            f32x4 a0 = {0.f, 0.f, 0.f, 0.f}, a1 = {0.f, 0.f, 0.f, 0.f};
#pragma unroll
            for (int ks = 0; ks < 4; ++ks) {
                a0 = __builtin_amdgcn_mfma_f32_16x16x32_bf16(afr[0][ks], b[ks], a0, 0, 0, 0);
                a1 = __builtin_amdgcn_mfma_f32_16x16x32_bf16(afr[1][ks], b[ks], a1, 0, 0, 0);
            }
#pragma unroll
            for (int r = 0; r < 4; ++r) {
                float v0 = a0[r], v1 = a1[r];
                lsum[nt] += v0 + v1;
                lsq[nt] += v0 * v0 + v1 * v1;
                hx[nt] = fmaxf(hx[nt], fmaxf(v0, v1));
                hn[nt] = fminf(hn[nt], fminf(v0, v1));
            }
            u32x2 pk0, pk1;
            pk0[0] = (unsigned)bfb(a0[0]) | ((unsigned)bfb(a0[1]) << 16);
            pk0[1] = (unsigned)bfb(a0[2]) | ((unsigned)bfb(a0[3]) << 16);
            pk1[0] = (unsigned)bfb(a1[0]) | ((unsigned)bfb(a1[1]) << 16);
            pk1[1] = (unsigned)bfb(a1[2]) | ((unsigned)bfb(a1[3]) << 16);
            int off = ((oct * 4 + nt) * 64 + lane) * 8;
            *(u32x2*)(hblk0 + off) = pk0;
            *(u32x2*)(hblk1 + off) = pk1;
        }
    }
    __syncthreads();
#pragma unroll
    for (int nt = 0; nt < 4; ++nt) {
        atomicAdd(&ssum[nt * 16 + lr], lsum[nt]);
        atomicAdd(&ssq[nt * 16 + lr], lsq[nt]);
        atomicMax(&smax[nt * 16 + lr], fkey(hx[nt]));
        atomicMin(&smin[nt * 16 + lr], fkey(hn[nt]));
    }
    __syncthreads();
    if (tid < 64) {
        float* b = bins + (size_t)(blockIdx.x & (NBINS - 1)) * 128;
        atomicAdd(&b[tid], ssum[tid]);
        atomicAdd(&b[64 + tid], ssq[tid]);
        atomicMax(&chmax[tid], smax[tid]);
        atomicMin(&chmin[tid], smin[tid]);
    }
}

// ---- finalize BN1: ab = (a,b), plus quant range from h min/max ----
__global__ void finalize_bn1(const float* __restrict__ bins,
                             const float* __restrict__ gamma,
                             const float* __restrict__ beta,
                             const unsigned* __restrict__ chmax,
                             const unsigned* __restrict__ chmin,
                             float* __restrict__ ab,
                             float* __restrict__ sinv, float* __restrict__ scl,
                             float invN) {
    int c = threadIdx.x;  // 64 threads
    float s = 0.f, q = 0.f;
    for (int b = 0; b < NBINS; ++b) { s += bins[b * 128 + c]; q += bins[b * 128 + 64 + c]; }
    float mu = s * invN;
    float var = q * invN - mu * mu;
    float rstd = rsqrtf(var + 1e-5f);
    float a = gamma[c] * rstd;
    float b = beta[c] - mu * a;
    ab[c] = a;
    ab[64 + c] = b;
    float hmx = fdec(chmax[c]), hmn = fdec(chmin[c]);
    float t0 = a * hmx + b, t1 = a * hmn + b;
    float fhi = elu_f(fmaxf(t0, t1));
    float flo = elu_f(fminf(t0, t1));
    float chabs = fmaxf(fmaxf(fhi, -flo), 1e-6f) * 1.005f;  // bf16-rounding margin
    sinv[c] = 127.f / chabs;
    scl[c] = chabs * (1.f / 127.f);
}

// ---- finalize BN2 ----
__global__ void finalize_stats(const float* __restrict__ bins,
                               const float* __restrict__ gamma,
                               const float* __restrict__ beta,
                               float* __restrict__ ab, float invN) {
    int c = threadIdx.x;  // 64 threads
    float s = 0.f, q = 0.f;
    for (int b = 0; b < NBINS; ++b) { s += bins[b * 128 + c]; q += bins[b * 128 + 64 + c]; }
    float mu = s * invN;
    float var = q * invN - mu * mu;
    float rstd = rsqrtf(var + 1e-5f);
    float a = gamma[c] * rstd;
    ab[c] = a;
    ab[64 + c] = beta[c] - mu * a;
}

// ---- prep_w8: fold per-channel y scale into int8 W_conv ----
__global__ __launch_bounds__(256) void prep_w8(const float* __restrict__ wcv,
                                               const float* __restrict__ scl,
                                               signed char* __restrict__ w8) {
    __shared__ float scl_s[64];
    __shared__ float red[4];
    __shared__ float tds;
    int d = blockIdx.x, t = threadIdx.x;
    if (t < 64) scl_s[t] = scl[t];
    __syncthreads();
    float m = 0.f;
    for (int i = t; i < 1728; i += 256) m = fmaxf(m, fabsf(wcv[i * 64 + d]) * scl_s[i & 63]);
#pragma unroll
    for (int dd = 1; dd < 64; dd <<= 1) m = fmaxf(m, __shfl_xor(m, dd));
    if ((t & 63) == 0) red[t >> 6] = m;
    __syncthreads();
    if (t == 0) {
        float mm = fmaxf(fmaxf(red[0], red[1]), fmaxf(red[2], red[3]));
        tds = 127.f / fmaxf(mm, 1e-20f);
    }
    __syncthreads();
    float T = tds;
    for (int i = t; i < 1728; i += 256) {
        int k = i >> 6, c = i & 63;
        float v = wcv[i * 64 + d] * scl_s[c] * T;
        w8[k * 4096 + d * 64 + c] = (signed char)(int)rintf(v);
    }
}

// ---- quant_pack: stream fragment region, BN+ELU+quant, LDS transpose,
// packed 64-B y8 rows written IN PLACE over the block's own region ----
__global__ __launch_bounds__(256) void quant_pack(char* __restrict__ hbuf,
                                                  const float* __restrict__ ab,
                                                  const float* __restrict__ sinv) {
    __shared__ char y8t[128][68];
    __shared__ float a_s[64], b_s[64], s_s[64];
    int tid = threadIdx.x;
    if (tid < 64) { a_s[tid] = ab[tid]; b_s[tid] = ab[64 + tid]; s_s[tid] = sinv[tid]; }
    __syncthreads();

    char* reg = hbuf + (size_t)blockIdx.x * 16384;
#pragma unroll
    for (int j = 0; j < 4; ++j) {
        u32x4 v = *(const u32x4*)(reg + j * 4096 + tid * 16);
        int u0 = j * 512 + tid * 2;
#pragma unroll
        for (int half = 0; half < 2; ++half) {
            int u = u0 + half;
            unsigned w0 = v[half * 2], w1 = v[half * 2 + 1];
            int w8i = u >> 8, nt = (u >> 6) & 3, ln = u & 63;
            int lr = ln & 15, lg = ln >> 4;
            int col = nt * 16 + lr;
            float a = a_s[col], b = b_s[col], s = s_s[col];
            int cb = lg * 32 + w8i;
            float fr[4];
            fr[0] = __uint_as_float(w0 << 16);
            fr[1] = __uint_as_float(w0 & 0xFFFF0000u);
            fr[2] = __uint_as_float(w1 << 16);
            fr[3] = __uint_as_float(w1 & 0xFFFF0000u);
#pragma unroll
            for (int r = 0; r < 4; ++r) {
                float f = fr[r] * a + b;
                float vq = elu_f(f) * s;
                vq = fminf(fmaxf(vq, -127.f), 127.f);
                int q = (int)rintf(vq);
                y8t[cb + r * 8][col] = (char)q;
            }
        }
    }
    __syncthreads();
    int cl = tid >> 1, half = tid & 1;
    unsigned wv[8];
#pragma unroll
    for (int j = 0; j < 8; ++j)
        wv[j] = *(const unsigned*)(&y8t[cl][half * 32 + j * 4]);
    u32x4 v0, v1;
#pragma unroll
    for (int j = 0; j < 4; ++j) { v0[j] = wv[j]; v1[j] = wv[4 + j]; }
    char* dst = reg + cl * 64 + half * 32;
    *(u32x4*)dst = v0;
    *(u32x4*)(dst + 16) = v1;
}

// ---- kernel C: 27-tap gather conv, packed rows, i32 accum ----
// ACC16: raw acc stored bf16 to accb; else f32 to outf.
template <bool ACC16>
__global__ __launch_bounds__(256, 4) void conv_bn_stats(
    const char* __restrict__ ybuf, const int* __restrict__ neigh,
    const signed char* __restrict__ w8,
    float* __restrict__ outf, unsigned short* __restrict__ accb,
    float* __restrict__ bins) {
    __shared__ __align__(16) int idxb_s[4][32 * TAPS];
    __shared__ float ssum[64], ssq[64];
    int tid = threadIdx.x;
    int wave = tid >> 6, lane = tid & 63, lr = lane & 15, lg = lane >> 4;
    int wr0 = blockIdx.x * 128 + wave * 32;

    if (tid < 64) { ssum[tid] = 0.f; ssq[tid] = 0.f; }

    int* idxb = idxb_s[wave];

    {
        int base_w = wr0 * TAPS;
#pragma unroll
        for (int j = 0; j < 14; ++j) {
            int w = j * 64 + lane;
            if (w < 32 * TAPS) idxb[w] = neigh[base_w + w];
        }
    }
    asm volatile("s_waitcnt vmcnt(0) lgkmcnt(0)" ::: "memory");
    __builtin_amdgcn_sched_barrier(0);

#define YADDR(idx) (((size_t)((unsigned)(idx) >> 7) << 14) + (((unsigned)(idx) & 127u) << 6))

    i32x4 iacc[2][4];
#pragma unroll
    for (int mt = 0; mt < 2; ++mt)
#pragma unroll
        for (int nt = 0; nt < 4; ++nt) iacc[mt][nt] = (i32x4){0, 0, 0, 0};

    const signed char* w8l = w8 + lr * 64 + lg * 16;   // B-fragment base

    i32x4 abuf[2][2];
    i32x4 bbuf[2][4];
    int icur[2];

    {
        int i00 = idxb[lr * TAPS + 0], i01 = idxb[(16 + lr) * TAPS + 0];
        abuf[0][0] = *(const i32x4*)(ybuf + YADDR(i00) + lg * 16);
        abuf[0][1] = *(const i32x4*)(ybuf + YADDR(i01) + lg * 16);
#pragma unroll
        for (int nt = 0; nt < 4; ++nt) bbuf[0][nt] = *(const i32x4*)(w8l + nt * 1024);
        __builtin_amdgcn_sched_barrier(0);
        int i10 = idxb[lr * TAPS + 1], i11 = idxb[(16 + lr) * TAPS + 1];
        abuf[1][0] = *(const i32x4*)(ybuf + YADDR(i10) + lg * 16);
        abuf[1][1] = *(const i32x4*)(ybuf + YADDR(i11) + lg * 16);
#pragma unroll
        for (int nt = 0; nt < 4; ++nt) bbuf[1][nt] = *(const i32x4*)(w8l + 4096 + nt * 1024);
        __builtin_amdgcn_sched_barrier(0);
        icur[0] = idxb[lr * TAPS + 2];
        icur[1] = idxb[(16 + lr) * TAPS + 2];
    }

#pragma unroll
    for (int k = 0; k < TAPS; ++k) {
        const int p = k & 1;
        if (k < TAPS - 1) { asm volatile("s_waitcnt vmcnt(6)" ::: "memory"); }
        else              { asm volatile("s_waitcnt vmcnt(0)" ::: "memory"); }
        __builtin_amdgcn_sched_barrier(0);
#pragma unroll
        for (int nt = 0; nt < 4; ++nt) {
            iacc[0][nt] = __builtin_amdgcn_mfma_i32_16x16x64_i8(abuf[p][0], bbuf[p][nt], iacc[0][nt], 0, 0, 0);
            iacc[1][nt] = __builtin_amdgcn_mfma_i32_16x16x64_i8(abuf[p][1], bbuf[p][nt], iacc[1][nt], 0, 0, 0);
        }
        if (k + 2 < TAPS) {
            abuf[p][0] = *(const i32x4*)(ybuf + YADDR(icur[0]) + lg * 16);
            abuf[p][1] = *(const i32x4*)(ybuf + YADDR(icur[1]) + lg * 16);
#pragma unroll
            for (int nt = 0; nt < 4; ++nt)
                bbuf[p][nt] = *(const i32x4*)(w8l + (k + 2) * 4096 + nt * 1024);
            if (k + 3 < TAPS) {
                icur[0] = idxb[lr * TAPS + (k + 3)];
                icur[1] = idxb[(16 + lr) * TAPS + (k + 3)];
            }
        }
    }

    float lsum[4] = {0.f, 0.f, 0.f, 0.f}, lsq[4] = {0.f, 0.f, 0.f, 0.f};
#pragma unroll
    for (int mt = 0; mt < 2; ++mt)
#pragma unroll
        for (int nt = 0; nt < 4; ++nt)
#pragma unroll
            for (int r = 0; r < 4; ++r) {
                float v = (float)iacc[mt][nt][r];
                int row = wr0 + mt * 16 + lg * 4 + r;
                if (ACC16) accb[(size_t)row * C_OUT + nt * 16 + lr] = bfb(v);
                else       outf[(size_t)row * C_OUT + nt * 16 + lr] = v;
                lsum[nt] += v; lsq[nt] += v * v;
            }
    __syncthreads();
#pragma unroll
    for (int nt = 0; nt < 4; ++nt) {
        atomicAdd(&ssum[nt * 16 + lr], lsum[nt]);
        atomicAdd(&ssq[nt * 16 + lr], lsq[nt]);
    }
    __syncthreads();
    if (tid < 64) {
        float* b = bins + (size_t)(blockIdx.x & (NBINS - 1)) * 128;
        atomicAdd(&b[tid], ssum[tid]);
        atomicAdd(&b[64 + tid], ssq[tid]);
    }
}

// ---- BN2 + ELU, f32 acc in place ----
__global__ __launch_bounds__(256) void bn_elu_out_f32(float* __restrict__ out,
                                                      const float* __restrict__ ab) {
    int tid = blockIdx.x * 256 + threadIdx.x;
    int c0 = (tid * 4) & 63;
    float av[4], bv[4];
#pragma unroll
    for (int j = 0; j < 4; ++j) { av[j] = ab[c0 + j]; bv[j] = ab[64 + c0 + j]; }
#pragma unroll
    for (int t = 0; t < 8; ++t) {
        size_t e = ((size_t)t * 1048576 + tid) * 4;
        f32x4 v = *(const f32x4*)(out + e);
        f32x4 o;
#pragma unroll
        for (int j = 0; j < 4; ++j) o[j] = elu_f(v[j] * av[j] + bv[j]);
        *(f32x4*)(out + e) = o;
    }
}

// ---- BN2 + ELU, bf16 acc -> f32 out ----
__global__ __launch_bounds__(256) void bn_elu_out_bf16(
    const unsigned short* __restrict__ accb, float* __restrict__ out,
    const float* __restrict__ ab) {
    int tid = blockIdx.x * 256 + threadIdx.x;
    int c0 = (tid * 8) & 63;
    float av[8], bv[8];
#pragma unroll
    for (int j = 0; j < 8; ++j) { av[j] = ab[c0 + j]; bv[j] = ab[64 + c0 + j]; }
#pragma unroll
    for (int t = 0; t < 4; ++t) {
        size_t e = ((size_t)t * 1048576 + tid) * 8;
        u32x4 v = *(const u32x4*)(accb + e);
        f32x4 o0, o1;
#pragma unroll
        for (int j = 0; j < 4; ++j) {
            unsigned w = v[j];
            float f0 = __uint_as_float(w << 16);
            float f1 = __uint_as_float(w & 0xFFFF0000u);
            float r0 = elu_f(f0 * av[j * 2] + bv[j * 2]);
            float r1 = elu_f(f1 * av[j * 2 + 1] + bv[j * 2 + 1]);
            if (j < 2) { o0[j * 2] = r0; o0[j * 2 + 1] = r1; }
            else       { o1[(j - 2) * 2] = r0; o1[(j - 2) * 2 + 1] = r1; }
        }
        *(f32x4*)(out + e) = o0;
        *(f32x4*)(out + e + 4) = o1;
    }
}

extern "C" void kernel_launch(void* const* d_in, const int* in_sizes, int n_in,
                              void* d_out, int out_size, void* d_ws, size_t ws_size,
                              hipStream_t stream) {
    const float* x     = (const float*)d_in[0];
    const int*   neigh = (const int*)d_in[1];
    const float* wup   = (const float*)d_in[2];
    const float* wcv   = (const float*)d_in[3];
    const float* g1    = (const float*)d_in[4];
    const float* b1    = (const float*)d_in[5];
    const float* g2    = (const float*)d_in[6];
    const float* b2    = (const float*)d_in[7];
    float* out = (float*)d_out;

    char* ws = (char*)d_ws;
    char*        hbuf  = ws + H_OFF;
    __bf16*      wtup  = (__bf16*)(ws + WTUP_OFF);
    signed char* w8    = (signed char*)(ws + W8CV_OFF);
    unsigned*    chmax = (unsigned*)(ws + CHMAX_OFF);
    unsigned*    chmin = (unsigned*)(ws + CHMIN_OFF);
    float*       sinv  = (float*)(ws + SINV_OFF);
    float*       scl   = (float*)(ws + SCL_OFF);
    float*       bins1 = (float*)(ws + S1_OFF);
    float*       bins2 = (float*)(ws + S2_OFF);
    float*       ab1   = (float*)(ws + AB1_OFF);
    float*       ab2   = (float*)(ws + AB2_OFF);
    unsigned short* accb = (unsigned short*)(ws + ACC16_OFF);

    const bool big = (ws_size >= (size_t)WS_NEED_BIG);

    hipMemsetAsync(ws + CHMAX_OFF, 0, ZERO_LEN, stream);
    hipMemsetAsync(ws + CHMIN_OFF, 0xFF, 256, stream);   // chmin init = +inf key

    prep_wup<<<256, 256, 0, stream>>>(wup, wtup);
    deconv_bn_stats<<<N_PARENT / 32, 256, 0, stream>>>(x, wtup, hbuf, bins1, chmax, chmin);
    finalize_bn1<<<1, 64, 0, stream>>>(bins1, g1, b1, chmax, chmin, ab1, sinv, scl, 1.f / (float)N_CHILD);
    prep_w8<<<64, 256, 0, stream>>>(wcv, scl, w8);
    quant_pack<<<N_PARENT / 16, 256, 0, stream>>>(hbuf, ab1, sinv);
    if (big) {
        conv_bn_stats<true><<<N_CHILD / 128, 256, 0, stream>>>((const char*)hbuf, neigh, w8, out, accb, bins2);
        finalize_stats<<<1, 64, 0, stream>>>(bins2, g2, b2, ab2, 1.f / (float)N_CHILD);
        bn_elu_out_bf16<<<4096, 256, 0, stream>>>(accb, out, ab2);
    } else {
        conv_bn_stats<false><<<N_CHILD / 128, 256, 0, stream>>>((const char*)hbuf, neigh, w8, out, accb, bins2);
        finalize_stats<<<1, 64, 0, stream>>>(bins2, g2, b2, ab2, 1.f / (float)N_CHILD);
        bn_elu_out_f32<<<4096, 256, 0, stream>>>(out, ab2);
    }
}

// Round 14
// 398.573 us; speedup vs baseline: 1.2489x; 1.0225x over previous
//
#include <hip/hip_runtime.h>

// UpBlock: deconv(8-oct GEMM) -> BN+ELU -> 27-tap gather conv -> BN+ELU
// R14: launch consolidation. Stats-buffer init folded into prep_wup (drops
// 2 memsets); finalize_bn1 + prep_w8 fused (64 blocks, redundant per-block
// BN1 finalize from L2-resident bins). 11 enqueues -> 7. Math unchanged.

#define N_PARENT 65536
#define C_IN     128
#define C_OUT    64
#define N_CHILD  (N_PARENT * 8)
#define TAPS     27
#define NBINS    64

typedef __bf16 bf16x8 __attribute__((ext_vector_type(8)));
typedef float  f32x4  __attribute__((ext_vector_type(4)));
typedef int    i32x4  __attribute__((ext_vector_type(4)));
typedef unsigned u32x2 __attribute__((ext_vector_type(2)));
typedef unsigned u32x4 __attribute__((ext_vector_type(4)));

// workspace layout (bytes)
#define H_OFF     0u          // hfrag [4096 reg][16384B]; later y8-in-place
#define WTUP_OFF  67108864u   // bf16 WtUp [8][64 n][128 k] = 131072
#define W8CV_OFF  67239936u   // i8 Wt8 [27][64 d][64 c] = 110592
#define CHMAX_OFF 67350528u   // u32 keyed per-channel max of h [64] = 256
#define CHMIN_OFF 67350784u   // u32 keyed per-channel min of h [64] = 256
#define SINV_OFF  67351040u   // f32 127/chabs [64] = 256
#define S1_OFF    67351552u   // f32 bins1 [64][128] = 32768
#define S2_OFF    67384320u   // f32 bins2 [64][128] = 32768
#define AB1_OFF   67417088u   // f32 a1[64], b1[64] = 512
#define AB2_OFF   67417600u   // f32 a2[64], b2[64] = 512
#define ACC16_OFF 67418112u   // bf16 acc [N_CHILD][64] = 67108864 (optional)
#define WS_NEED_BIG (ACC16_OFF + 67108864u)

__device__ __forceinline__ float elu_f(float f) {
    return f > 0.f ? f : (__expf(f) - 1.f);
}
// order-preserving float<->uint key for atomic max/min on signed floats
__device__ __forceinline__ unsigned fkey(float f) {
    unsigned b = __float_as_uint(f);
    return (b & 0x80000000u) ? ~b : (b | 0x80000000u);
}
__device__ __forceinline__ float fdec(unsigned k) {
    unsigned b = (k & 0x80000000u) ? (k & 0x7fffffffu) : ~k;
    return __uint_as_float(b);
}
__device__ __forceinline__ unsigned short bfb(float v) {
    __bf16 b = (__bf16)v;
    union { __bf16 b; unsigned short u; } c;
    c.b = b;
    return c.u;
}

// ---- prep: WtUp transpose -> bf16; also init stats buffers (no memsets) ----
__global__ __launch_bounds__(256) void prep_wup(const float* __restrict__ wup,
                                                __bf16* __restrict__ wtup,
                                                float* __restrict__ bins1,
                                                float* __restrict__ bins2,
                                                unsigned* __restrict__ chmax,
                                                unsigned* __restrict__ chmin) {
    int i = blockIdx.x * 256 + threadIdx.x;        // 65536
    int o = i >> 13, rem = i & 8191, n = rem >> 7, k = rem & 127;
    wtup[i] = (__bf16)wup[o * 8192 + k * 64 + n];
    if (i < 8192) { bins1[i] = 0.f; bins2[i] = 0.f; }
    if (i < 64)   { chmax[i] = 0u; chmin[i] = 0xFFFFFFFFu; }
}

// ---- kernel A: h = x @ W_up, 32 parents/block, B-frag reuse x2 ----
__global__ __launch_bounds__(256, 4) void deconv_bn_stats(
    const float* __restrict__ x, const __bf16* __restrict__ wtup,
    char* __restrict__ hfrag, float* __restrict__ bins,
    unsigned* __restrict__ chmax, unsigned* __restrict__ chmin) {
    __shared__ float ssum[64], ssq[64];
    __shared__ unsigned smax[64], smin[64];
    int tid = threadIdx.x;
    int wave = tid >> 6, lane = tid & 63, lr = lane & 15, lg = lane >> 4;
    int p0 = blockIdx.x * 32;

    if (tid < 64) { ssum[tid] = 0.f; ssq[tid] = 0.f; smax[tid] = 0u; smin[tid] = 0xFFFFFFFFu; }

    // A-fragments for both 16-parent groups
    bf16x8 afr[2][4];
#pragma unroll
    for (int g = 0; g < 2; ++g) {
        const float* xrow = x + (size_t)(p0 + g * 16 + lr) * C_IN;
#pragma unroll
        for (int ks = 0; ks < 4; ++ks) {
            const float* src = xrow + ks * 32 + lg * 8;
            f32x4 u0 = *(const f32x4*)(src);
            f32x4 u1 = *(const f32x4*)(src + 4);
            bf16x8 a;
#pragma unroll
            for (int i = 0; i < 4; ++i) { a[i] = (__bf16)u0[i]; a[4 + i] = (__bf16)u1[i]; }
            afr[g][ks] = a;
        }
    }

    char* hblk0 = hfrag + (size_t)(blockIdx.x * 2) * 16384;
    char* hblk1 = hblk0 + 16384;

    float lsum[4] = {0.f, 0.f, 0.f, 0.f}, lsq[4] = {0.f, 0.f, 0.f, 0.f};
    float hx[4] = {-3e38f, -3e38f, -3e38f, -3e38f};
    float hn[4] = {3e38f, 3e38f, 3e38f, 3e38f};
#pragma unroll
    for (int oo = 0; oo < 2; ++oo) {
        int oct = wave * 2 + oo;
#pragma unroll
        for (int nt = 0; nt < 4; ++nt) {
            bf16x8 b[4];
#pragma unroll
            for (int ks = 0; ks < 4; ++ks)
                b[ks] = *(const bf16x8*)(wtup + ((size_t)(oct * 64 + nt * 16 + lr) * C_IN + ks * 32 + lg * 8));
            f32x4 a0 = {0.f, 0.f, 0.f, 0.f}, a1 = {0.f, 0.f, 0.f, 0.f};
#pragma unroll
            for (int ks = 0; ks < 4; ++ks) {
                a0 = __builtin_amdgcn_mfma_f32_16x16x32_bf16(afr[0][ks], b[ks], a0, 0, 0, 0);
                a1 = __builtin_amdgcn_mfma_f32_16x16x32_bf16(afr[1][ks], b[ks], a1, 0, 0, 0);
            }
#pragma unroll
            for (int r = 0; r < 4; ++r) {
                float v0 = a0[r], v1 = a1[r];
                lsum[nt] += v0 + v1;
                lsq[nt] += v0 * v0 + v1 * v1;
                hx[nt] = fmaxf(hx[nt], fmaxf(v0, v1));
                hn[nt] = fminf(hn[nt], fminf(v0, v1));
            }
            u32x2 pk0, pk1;
            pk0[0] = (unsigned)bfb(a0[0]) | ((unsigned)bfb(a0[1]) << 16);
            pk0[1] = (unsigned)bfb(a0[2]) | ((unsigned)bfb(a0[3]) << 16);
            pk1[0] = (unsigned)bfb(a1[0]) | ((unsigned)bfb(a1[1]) << 16);
            pk1[1] = (unsigned)bfb(a1[2]) | ((unsigned)bfb(a1[3]) << 16);
            int off = ((oct * 4 + nt) * 64 + lane) * 8;
            *(u32x2*)(hblk0 + off) = pk0;
            *(u32x2*)(hblk1 + off) = pk1;
        }
    }
    __syncthreads();
#pragma unroll
    for (int nt = 0; nt < 4; ++nt) {
        atomicAdd(&ssum[nt * 16 + lr], lsum[nt]);
        atomicAdd(&ssq[nt * 16 + lr], lsq[nt]);
        atomicMax(&smax[nt * 16 + lr], fkey(hx[nt]));
        atomicMin(&smin[nt * 16 + lr], fkey(hn[nt]));
    }
    __syncthreads();
    if (tid < 64) {
        float* b = bins + (size_t)(blockIdx.x & (NBINS - 1)) * 128;
        atomicAdd(&b[tid], ssum[tid]);
        atomicAdd(&b[64 + tid], ssq[tid]);
        atomicMax(&chmax[tid], smax[tid]);
        atomicMin(&chmin[tid], smin[tid]);
    }
}

// ---- fused finalize BN1 + W8 quantization (64 blocks, one per column d) ----
// Every block redundantly recomputes the 64-channel BN1 finalize from the
// L2-resident bins; block 0 publishes ab1/sinv for quant_pack.
__global__ __launch_bounds__(256) void finalize1_w8(
    const float* __restrict__ bins,
    const float* __restrict__ gamma, const float* __restrict__ beta,
    const unsigned* __restrict__ chmax, const unsigned* __restrict__ chmin,
    const float* __restrict__ wcv, signed char* __restrict__ w8,
    float* __restrict__ ab, float* __restrict__ sinv, float invN) {
    __shared__ float scl_s[64];
    __shared__ float red[4];
    __shared__ float tds;
    int d = blockIdx.x, t = threadIdx.x;
    if (t < 64) {
        float s = 0.f, q = 0.f;
#pragma unroll
        for (int b = 0; b < NBINS; ++b) { s += bins[b * 128 + t]; q += bins[b * 128 + 64 + t]; }
        float mu = s * invN;
        float var = q * invN - mu * mu;
        float rstd = rsqrtf(var + 1e-5f);
        float a = gamma[t] * rstd;
        float bb = beta[t] - mu * a;
        float hmx = fdec(chmax[t]), hmn = fdec(chmin[t]);
        float t0 = a * hmx + bb, t1 = a * hmn + bb;
        float fhi = elu_f(fmaxf(t0, t1));
        float flo = elu_f(fminf(t0, t1));
        float chabs = fmaxf(fmaxf(fhi, -flo), 1e-6f) * 1.005f;
        scl_s[t] = chabs * (1.f / 127.f);
        if (d == 0) { ab[t] = a; ab[64 + t] = bb; sinv[t] = 127.f / chabs; }
    }
    __syncthreads();
    float m = 0.f;
    for (int i = t; i < 1728; i += 256) m = fmaxf(m, fabsf(wcv[i * 64 + d]) * scl_s[i & 63]);
#pragma unroll
    for (int dd = 1; dd < 64; dd <<= 1) m = fmaxf(m, __shfl_xor(m, dd));
    if ((t & 63) == 0) red[t >> 6] = m;
    __syncthreads();
    if (t == 0) {
        float mm = fmaxf(fmaxf(red[0], red[1]), fmaxf(red[2], red[3]));
        tds = 127.f / fmaxf(mm, 1e-20f);
    }
    __syncthreads();
    float T = tds;
    for (int i = t; i < 1728; i += 256) {
        int k = i >> 6, c = i & 63;
        float v = wcv[i * 64 + d] * scl_s[c] * T;
        w8[k * 4096 + d * 64 + c] = (signed char)(int)rintf(v);
    }
}

// ---- finalize BN2 ----
__global__ void finalize_stats(const float* __restrict__ bins,
                               const float* __restrict__ gamma,
                               const float* __restrict__ beta,
                               float* __restrict__ ab, float invN) {
    int c = threadIdx.x;  // 64 threads
    float s = 0.f, q = 0.f;
#pragma unroll
    for (int b = 0; b < NBINS; ++b) { s += bins[b * 128 + c]; q += bins[b * 128 + 64 + c]; }
    float mu = s * invN;
    float var = q * invN - mu * mu;
    float rstd = rsqrtf(var + 1e-5f);
    float a = gamma[c] * rstd;
    ab[c] = a;
    ab[64 + c] = beta[c] - mu * a;
}

// ---- quant_pack: stream fragment region, BN+ELU+quant, LDS transpose,
// packed 64-B y8 rows written IN PLACE over the block's own region ----
__global__ __launch_bounds__(256) void quant_pack(char* __restrict__ hbuf,
                                                  const float* __restrict__ ab,
                                                  const float* __restrict__ sinv) {
    __shared__ char y8t[128][68];
    __shared__ float a_s[64], b_s[64], s_s[64];
    int tid = threadIdx.x;
    if (tid < 64) { a_s[tid] = ab[tid]; b_s[tid] = ab[64 + tid]; s_s[tid] = sinv[tid]; }
    __syncthreads();

    char* reg = hbuf + (size_t)blockIdx.x * 16384;
#pragma unroll
    for (int j = 0; j < 4; ++j) {
        u32x4 v = *(const u32x4*)(reg + j * 4096 + tid * 16);
        int u0 = j * 512 + tid * 2;
#pragma unroll
        for (int half = 0; half < 2; ++half) {
            int u = u0 + half;
            unsigned w0 = v[half * 2], w1 = v[half * 2 + 1];
            int w8i = u >> 8, nt = (u >> 6) & 3, ln = u & 63;
            int lr = ln & 15, lg = ln >> 4;
            int col = nt * 16 + lr;
            float a = a_s[col], b = b_s[col], s = s_s[col];
            int cb = lg * 32 + w8i;
            float fr[4];
            fr[0] = __uint_as_float(w0 << 16);
            fr[1] = __uint_as_float(w0 & 0xFFFF0000u);
            fr[2] = __uint_as_float(w1 << 16);
            fr[3] = __uint_as_float(w1 & 0xFFFF0000u);
#pragma unroll
            for (int r = 0; r < 4; ++r) {
                float f = fr[r] * a + b;
                float vq = elu_f(f) * s;
                vq = fminf(fmaxf(vq, -127.f), 127.f);
                int q = (int)rintf(vq);
                y8t[cb + r * 8][col] = (char)q;
            }
        }
    }
    __syncthreads();
    int cl = tid >> 1, half = tid & 1;
    unsigned wv[8];
#pragma unroll
    for (int j = 0; j < 8; ++j)
        wv[j] = *(const unsigned*)(&y8t[cl][half * 32 + j * 4]);
    u32x4 v0, v1;
#pragma unroll
    for (int j = 0; j < 4; ++j) { v0[j] = wv[j]; v1[j] = wv[4 + j]; }
    char* dst = reg + cl * 64 + half * 32;
    *(u32x4*)dst = v0;
    *(u32x4*)(dst + 16) = v1;
}

// ---- kernel C: 27-tap gather conv, packed rows, i32 accum ----
// ACC16: raw acc stored bf16 to accb; else f32 to outf.
template <bool ACC16>
__global__ __launch_bounds__(256, 4) void conv_bn_stats(
    const char* __restrict__ ybuf, const int* __restrict__ neigh,
    const signed char* __restrict__ w8,
    float* __restrict__ outf, unsigned short* __restrict__ accb,
    float* __restrict__ bins) {
    __shared__ __align__(16) int idxb_s[4][32 * TAPS];
    __shared__ float ssum[64], ssq[64];
    int tid = threadIdx.x;
    int wave = tid >> 6, lane = tid & 63, lr = lane & 15, lg = lane >> 4;
    int wr0 = blockIdx.x * 128 + wave * 32;

    if (tid < 64) { ssum[tid] = 0.f; ssq[tid] = 0.f; }

    int* idxb = idxb_s[wave];

    {
        int base_w = wr0 * TAPS;
#pragma unroll
        for (int j = 0; j < 14; ++j) {
            int w = j * 64 + lane;
            if (w < 32 * TAPS) idxb[w] = neigh[base_w + w];
        }
    }
    asm volatile("s_waitcnt vmcnt(0) lgkmcnt(0)" ::: "memory");
    __builtin_amdgcn_sched_barrier(0);

#define YADDR(idx) (((size_t)((unsigned)(idx) >> 7) << 14) + (((unsigned)(idx) & 127u) << 6))

    i32x4 iacc[2][4];
#pragma unroll
    for (int mt = 0; mt < 2; ++mt)
#pragma unroll
        for (int nt = 0; nt < 4; ++nt) iacc[mt][nt] = (i32x4){0, 0, 0, 0};

    const signed char* w8l = w8 + lr * 64 + lg * 16;   // B-fragment base

    i32x4 abuf[2][2];
    i32x4 bbuf[2][4];
    int icur[2];

    {
        int i00 = idxb[lr * TAPS + 0], i01 = idxb[(16 + lr) * TAPS + 0];
        abuf[0][0] = *(const i32x4*)(ybuf + YADDR(i00) + lg * 16);
        abuf[0][1] = *(const i32x4*)(ybuf + YADDR(i01) + lg * 16);
#pragma unroll
        for (int nt = 0; nt < 4; ++nt) bbuf[0][nt] = *(const i32x4*)(w8l + nt * 1024);
        __builtin_amdgcn_sched_barrier(0);
        int i10 = idxb[lr * TAPS + 1], i11 = idxb[(16 + lr) * TAPS + 1];
        abuf[1][0] = *(const i32x4*)(ybuf + YADDR(i10) + lg * 16);
        abuf[1][1] = *(const i32x4*)(ybuf + YADDR(i11) + lg * 16);
#pragma unroll
        for (int nt = 0; nt < 4; ++nt) bbuf[1][nt] = *(const i32x4*)(w8l + 4096 + nt * 1024);
        __builtin_amdgcn_sched_barrier(0);
        icur[0] = idxb[lr * TAPS + 2];
        icur[1] = idxb[(16 + lr) * TAPS + 2];
    }

#pragma unroll
    for (int k = 0; k < TAPS; ++k) {
        const int p = k & 1;
        if (k < TAPS - 1) { asm volatile("s_waitcnt vmcnt(6)" ::: "memory"); }
        else              { asm volatile("s_waitcnt vmcnt(0)" ::: "memory"); }
        __builtin_amdgcn_sched_barrier(0);
#pragma unroll
        for (int nt = 0; nt < 4; ++nt) {
            iacc[0][nt] = __builtin_amdgcn_mfma_i32_16x16x64_i8(abuf[p][0], bbuf[p][nt], iacc[0][nt], 0, 0, 0);
            iacc[1][nt] = __builtin_amdgcn_mfma_i32_16x16x64_i8(abuf[p][1], bbuf[p][nt], iacc[1][nt], 0, 0, 0);
        }
        if (k + 2 < TAPS) {
            abuf[p][0] = *(const i32x4*)(ybuf + YADDR(icur[0]) + lg * 16);
            abuf[p][1] = *(const i32x4*)(ybuf + YADDR(icur[1]) + lg * 16);
#pragma unroll
            for (int nt = 0; nt < 4; ++nt)
                bbuf[p][nt] = *(const i32x4*)(w8l + (k + 2) * 4096 + nt * 1024);
            if (k + 3 < TAPS) {
                icur[0] = idxb[lr * TAPS + (k + 3)];
                icur[1] = idxb[(16 + lr) * TAPS + (k + 3)];
            }
        }
    }

    float lsum[4] = {0.f, 0.f, 0.f, 0.f}, lsq[4] = {0.f, 0.f, 0.f, 0.f};
#pragma unroll
    for (int mt = 0; mt < 2; ++mt)
#pragma unroll
        for (int nt = 0; nt < 4; ++nt)
#pragma unroll
            for (int r = 0; r < 4; ++r) {
                float v = (float)iacc[mt][nt][r];
                int row = wr0 + mt * 16 + lg * 4 + r;
                if (ACC16) accb[(size_t)row * C_OUT + nt * 16 + lr] = bfb(v);
                else       outf[(size_t)row * C_OUT + nt * 16 + lr] = v;
                lsum[nt] += v; lsq[nt] += v * v;
            }
    __syncthreads();
#pragma unroll
    for (int nt = 0; nt < 4; ++nt) {
        atomicAdd(&ssum[nt * 16 + lr], lsum[nt]);
        atomicAdd(&ssq[nt * 16 + lr], lsq[nt]);
    }
    __syncthreads();
    if (tid < 64) {
        float* b = bins + (size_t)(blockIdx.x & (NBINS - 1)) * 128;
        atomicAdd(&b[tid], ssum[tid]);
        atomicAdd(&b[64 + tid], ssq[tid]);
    }
}

// ---- BN2 + ELU, f32 acc in place ----
__global__ __launch_bounds__(256) void bn_elu_out_f32(float* __restrict__ out,
                                                      const float* __restrict__ ab) {
    int tid = blockIdx.x * 256 + threadIdx.x;
    int c0 = (tid * 4) & 63;
    float av[4], bv[4];
#pragma unroll
    for (int j = 0; j < 4; ++j) { av[j] = ab[c0 + j]; bv[j] = ab[64 + c0 + j]; }
#pragma unroll
    for (int t = 0; t < 8; ++t) {
        size_t e = ((size_t)t * 1048576 + tid) * 4;
        f32x4 v = *(const f32x4*)(out + e);
        f32x4 o;
#pragma unroll
        for (int j = 0; j < 4; ++j) o[j] = elu_f(v[j] * av[j] + bv[j]);
        *(f32x4*)(out + e) = o;
    }
}

// ---- BN2 + ELU, bf16 acc -> f32 out ----
__global__ __launch_bounds__(256) void bn_elu_out_bf16(
    const unsigned short* __restrict__ accb, float* __restrict__ out,
    const float* __restrict__ ab) {
    int tid = blockIdx.x * 256 + threadIdx.x;
    int c0 = (tid * 8) & 63;
    float av[8], bv[8];
#pragma unroll
    for (int j = 0; j < 8; ++j) { av[j] = ab[c0 + j]; bv[j] = ab[64 + c0 + j]; }
#pragma unroll
    for (int t = 0; t < 4; ++t) {
        size_t e = ((size_t)t * 1048576 + tid) * 8;
        u32x4 v = *(const u32x4*)(accb + e);
        f32x4 o0, o1;
#pragma unroll
        for (int j = 0; j < 4; ++j) {
            unsigned w = v[j];
            float f0 = __uint_as_float(w << 16);
            float f1 = __uint_as_float(w & 0xFFFF0000u);
            float r0 = elu_f(f0 * av[j * 2] + bv[j * 2]);
            float r1 = elu_f(f1 * av[j * 2 + 1] + bv[j * 2 + 1]);
            if (j < 2) { o0[j * 2] = r0; o0[j * 2 + 1] = r1; }
            else       { o1[(j - 2) * 2] = r0; o1[(j - 2) * 2 + 1] = r1; }
        }
        *(f32x4*)(out + e) = o0;
        *(f32x4*)(out + e + 4) = o1;
    }
}

extern "C" void kernel_launch(void* const* d_in, const int* in_sizes, int n_in,
                              void* d_out, int out_size, void* d_ws, size_t ws_size,
                              hipStream_t stream) {
    const float* x     = (const float*)d_in[0];
    const int*   neigh = (const int*)d_in[1];
    const float* wup   = (const float*)d_in[2];
    const float* wcv   = (const float*)d_in[3];
    const float* g1    = (const float*)d_in[4];
    const float* b1    = (const float*)d_in[5];
    const float* g2    = (const float*)d_in[6];
    const float* b2    = (const float*)d_in[7];
    float* out = (float*)d_out;

    char* ws = (char*)d_ws;
    char*        hbuf  = ws + H_OFF;
    __bf16*      wtup  = (__bf16*)(ws + WTUP_OFF);
    signed char* w8    = (signed char*)(ws + W8CV_OFF);
    unsigned*    chmax = (unsigned*)(ws + CHMAX_OFF);
    unsigned*    chmin = (unsigned*)(ws + CHMIN_OFF);
    float*       sinv  = (float*)(ws + SINV_OFF);
    float*       bins1 = (float*)(ws + S1_OFF);
    float*       bins2 = (float*)(ws + S2_OFF);
    float*       ab1   = (float*)(ws + AB1_OFF);
    float*       ab2   = (float*)(ws + AB2_OFF);
    unsigned short* accb = (unsigned short*)(ws + ACC16_OFF);

    const bool big = (ws_size >= (size_t)WS_NEED_BIG);

    prep_wup<<<256, 256, 0, stream>>>(wup, wtup, bins1, bins2, chmax, chmin);
    deconv_bn_stats<<<N_PARENT / 32, 256, 0, stream>>>(x, wtup, hbuf, bins1, chmax, chmin);
    finalize1_w8<<<64, 256, 0, stream>>>(bins1, g1, b1, chmax, chmin, wcv, w8, ab1, sinv,
                                         1.f / (float)N_CHILD);
    quant_pack<<<N_PARENT / 16, 256, 0, stream>>>(hbuf, ab1, sinv);
    if (big) {
        conv_bn_stats<true><<<N_CHILD / 128, 256, 0, stream>>>((const char*)hbuf, neigh, w8, out, accb, bins2);
        finalize_stats<<<1, 64, 0, stream>>>(bins2, g2, b2, ab2, 1.f / (float)N_CHILD);
        bn_elu_out_bf16<<<4096, 256, 0, stream>>>(accb, out, ab2);
    } else {
        conv_bn_stats<false><<<N_CHILD / 128, 256, 0, stream>>>((const char*)hbuf, neigh, w8, out, accb, bins2);
        finalize_stats<<<1, 64, 0, stream>>>(bins2, g2, b2, ab2, 1.f / (float)N_CHILD);
        bn_elu_out_f32<<<4096, 256, 0, stream>>>(out, ab2);
    }
}